// Round 15
// baseline (2942.701 us; speedup 1.0000x reference)
//
#include <hip/hip_runtime.h>
#include <stdint.h>

// ---------------- static problem config ----------------
#define S_TOT 21504
#define M_TOK 86016
// levels: (32,32) start 0, (64,64) start 1024, (128,128) start 5120

typedef __attribute__((ext_vector_type(8))) short bf16x8;
typedef __attribute__((ext_vector_type(4))) float f32x4;
typedef __attribute__((ext_vector_type(2))) float f32x2;

__device__ __forceinline__ unsigned short f2b(float f) {
  union { float f; unsigned u; } v; v.f = f;
  unsigned r = v.u + 0x7FFFu + ((v.u >> 16) & 1u);
  return (unsigned short)(r >> 16);
}
__device__ __forceinline__ float b2f(unsigned short h) {
  union { unsigned u; float f; } v; v.u = ((unsigned)h) << 16;
  return v.f;
}
__device__ __forceinline__ float blo(unsigned u) {
  union { unsigned u; float f; } v; v.u = u << 16; return v.f;
}
__device__ __forceinline__ float bhi(unsigned u) {
  union { unsigned u; float f; } v; v.u = u & 0xffff0000u; return v.f;
}
__device__ __forceinline__ f32x2 unpk(unsigned u) {
  union { unsigned u; float f; } lo, hi;
  lo.u = u << 16; hi.u = u & 0xffff0000u;
  return (f32x2){lo.f, hi.f};
}

#define LSTR 40

// ---------------- bf16 MFMA GEMM (round-14 form): C = A * Bt^T + bias ----------------
// BM=BN=128; grid x = col-tile (A reuse), y = row-tile. Coalesced C via LDS bounce.
template <int RELU>
__global__ __launch_bounds__(256) void gemm_kernel(
    const unsigned short* __restrict__ A, const unsigned short* __restrict__ Bt,
    const float* __restrict__ bias, const float* __restrict__ bias2, int nsplit,
    unsigned short* __restrict__ C, int N, int K) {
  __shared__ unsigned short Alds[128 * LSTR];
  __shared__ unsigned short Blds[128 * LSTR];
  const int tid = threadIdx.x;
  const int wave = tid >> 6, lane = tid & 63;
  const long m0 = (long)blockIdx.y * 128;
  const int n0 = blockIdx.x * 128;
  const int wm = (wave >> 1) * 64, wn = (wave & 1) * 64;

  f32x4 acc[4][4];
#pragma unroll
  for (int i = 0; i < 4; i++)
#pragma unroll
    for (int j = 0; j < 4; j++) acc[i][j] = (f32x4){0.f, 0.f, 0.f, 0.f};

  const int ar = tid >> 2, ak = (tid & 3) * 8;
  int brA = n0 + ar;      if (brA >= N) brA = N - 1;
  int brB = n0 + ar + 64; if (brB >= N) brB = N - 1;
  const unsigned short* a0p = A + (m0 + ar) * (long)K + ak;
  const unsigned short* a1p = A + (m0 + ar + 64) * (long)K + ak;
  const unsigned short* b0p = Bt + (long)brA * K + ak;
  const unsigned short* b1p = Bt + (long)brB * K + ak;
  unsigned short* aw0 = Alds + ar * LSTR + ak;
  unsigned short* aw1 = Alds + (ar + 64) * LSTR + ak;
  unsigned short* bw0 = Blds + ar * LSTR + ak;
  unsigned short* bw1 = Blds + (ar + 64) * LSTR + ak;

  uint4 a0 = *(const uint4*)a0p;
  uint4 a1 = *(const uint4*)a1p;
  uint4 b0 = *(const uint4*)b0p;
  uint4 b1 = *(const uint4*)b1p;

  for (int k0 = 0; k0 < K; k0 += 32) {
    if (k0) __syncthreads();
    *(uint4*)aw0 = a0;
    *(uint4*)aw1 = a1;
    *(uint4*)bw0 = b0;
    *(uint4*)bw1 = b1;
    if (k0 + 32 < K) {
      a0 = *(const uint4*)(a0p + k0 + 32);
      a1 = *(const uint4*)(a1p + k0 + 32);
      b0 = *(const uint4*)(b0p + k0 + 32);
      b1 = *(const uint4*)(b1p + k0 + 32);
    }
    __syncthreads();

    const int kk = (lane >> 4) * 8;
    bf16x8 af[4], bq[4];
#pragma unroll
    for (int i = 0; i < 4; i++)
      af[i] = *(const bf16x8*)&Alds[(wm + i * 16 + (lane & 15)) * LSTR + kk];
#pragma unroll
    for (int j = 0; j < 4; j++)
      bq[j] = *(const bf16x8*)&Blds[(wn + j * 16 + (lane & 15)) * LSTR + kk];
#pragma unroll
    for (int i = 0; i < 4; i++)
#pragma unroll
      for (int j = 0; j < 4; j++)
        acc[i][j] = __builtin_amdgcn_mfma_f32_16x16x32_bf16(af[i], bq[j], acc[i][j], 0, 0, 0);
  }

  // coalesced C-write via LDS bounce (64 rows x 136 stride)
  unsigned short* stage = Alds;
  const int colb = lane & 15, rowb = (lane >> 4) * 4;
#pragma unroll
  for (int half = 0; half < 2; half++) {
    __syncthreads();
    if (wm == half * 64) {
#pragma unroll
      for (int j = 0; j < 4; j++) {
        const int n = n0 + wn + j * 16 + colb;
        const float bn = (n < N) ? ((n < nsplit) ? bias[n] : bias2[n - nsplit]) : 0.f;
#pragma unroll
        for (int i = 0; i < 4; i++) {
#pragma unroll
          for (int r = 0; r < 4; r++) {
            float v = acc[i][j][r] + bn;
            if (RELU) v = fmaxf(v, 0.f);
            stage[(i * 16 + rowb + r) * 136 + wn + j * 16 + colb] = f2b(v);
          }
        }
      }
    }
    __syncthreads();
#pragma unroll
    for (int t = 0; t < 4; t++) {
      const int idx = t * 256 + tid;
      const int rr = idx >> 4;
      const int cc = (idx & 15) * 8;
      const int n = n0 + cc;
      if (n < N) {
        const long m = m0 + half * 64 + rr;
        *(uint4*)(C + m * N + n) = *(const uint4*)(stage + rr * 136 + cc);
      }
    }
  }
}

// ---------------- fused GEMM(N=256) + residual + LayerNorm ----------------
// BM=64, BN=256 (full row per block) -> LN in epilogue. Waves 2x2 (wm in {0,32},
// wn in {0,128}), acc 2x8. Epilogue: acc+bias -> bf16 LDS bounce (bit-identical to
// the old intermediate buffer path) -> per-wave 16-row LN (same math as resln).
__global__ __launch_bounds__(256) void gemm_ln_kernel(
    const unsigned short* __restrict__ A, const unsigned short* __restrict__ Bt,
    const float* __restrict__ bias, const unsigned short* __restrict__ x,
    const float* __restrict__ g, const float* __restrict__ bta,
    unsigned short* __restrict__ ob, const unsigned short* __restrict__ pos,
    unsigned short* __restrict__ qb, float* __restrict__ fout, int K) {
  __shared__ unsigned short smem[64 * 264];  // 33792 B; staging A(64*40)+B(256*40)=12800 fits
  unsigned short* Alds = smem;
  unsigned short* Blds = smem + 64 * LSTR;
  const int tid = threadIdx.x;
  const int wave = tid >> 6, lane = tid & 63;
  const long m0 = (long)blockIdx.x * 64;
  const int wm = (wave >> 1) * 32, wn = (wave & 1) * 128;
  const int l15 = lane & 15, lhi = lane >> 4;

  f32x4 acc[2][8];
#pragma unroll
  for (int i = 0; i < 2; i++)
#pragma unroll
    for (int j = 0; j < 8; j++) acc[i][j] = (f32x4){0.f, 0.f, 0.f, 0.f};

  // staging: A 64x32 = 256 chunks (1/thread); B 256x32 = 1024 chunks (4/thread)
  const int srow = tid >> 2, sk = (tid & 3) * 8;
  const unsigned short* apA = A + (m0 + srow) * (long)K + sk;
  const unsigned short* bp0 = Bt + (long)srow * K + sk;
  const unsigned short* bp1 = Bt + (long)(srow + 64) * K + sk;
  const unsigned short* bp2 = Bt + (long)(srow + 128) * K + sk;
  const unsigned short* bp3 = Bt + (long)(srow + 192) * K + sk;
  unsigned short* awp = Alds + srow * LSTR + sk;
  unsigned short* bwp0 = Blds + srow * LSTR + sk;
  unsigned short* bwp1 = Blds + (srow + 64) * LSTR + sk;
  unsigned short* bwp2 = Blds + (srow + 128) * LSTR + sk;
  unsigned short* bwp3 = Blds + (srow + 192) * LSTR + sk;

  uint4 ra = *(const uint4*)apA;
  uint4 rb0 = *(const uint4*)bp0;
  uint4 rb1 = *(const uint4*)bp1;
  uint4 rb2 = *(const uint4*)bp2;
  uint4 rb3 = *(const uint4*)bp3;

  for (int k0 = 0; k0 < K; k0 += 32) {
    if (k0) __syncthreads();
    *(uint4*)awp = ra;
    *(uint4*)bwp0 = rb0;
    *(uint4*)bwp1 = rb1;
    *(uint4*)bwp2 = rb2;
    *(uint4*)bwp3 = rb3;
    if (k0 + 32 < K) {
      ra = *(const uint4*)(apA + k0 + 32);
      rb0 = *(const uint4*)(bp0 + k0 + 32);
      rb1 = *(const uint4*)(bp1 + k0 + 32);
      rb2 = *(const uint4*)(bp2 + k0 + 32);
      rb3 = *(const uint4*)(bp3 + k0 + 32);
    }
    __syncthreads();

    const int kk = lhi * 8;
    bf16x8 af[2], bq[8];
#pragma unroll
    for (int i = 0; i < 2; i++)
      af[i] = *(const bf16x8*)&Alds[(wm + i * 16 + l15) * LSTR + kk];
#pragma unroll
    for (int j = 0; j < 8; j++)
      bq[j] = *(const bf16x8*)&Blds[(wn + j * 16 + l15) * LSTR + kk];
#pragma unroll
    for (int i = 0; i < 2; i++)
#pragma unroll
      for (int j = 0; j < 8; j++)
        acc[i][j] = __builtin_amdgcn_mfma_f32_16x16x32_bf16(af[i], bq[j], acc[i][j], 0, 0, 0);
  }

  // ---- epilogue: acc+bias -> bf16 stage (bit-identical to old intermediate) ----
  __syncthreads();  // all frag reads complete before smem is repurposed
  {
    const int rowb = lhi * 4;
#pragma unroll
    for (int j = 0; j < 8; j++) {
      const int n = wn + j * 16 + l15;
      const float bn = bias[n];
#pragma unroll
      for (int i = 0; i < 2; i++)
#pragma unroll
        for (int r = 0; r < 4; r++)
          smem[(wm + i * 16 + rowb + r) * 264 + n] = f2b(acc[i][j][r] + bn);
    }
  }
  __syncthreads();

  // ---- LN: wave handles rows [wave*16, wave*16+16); same math/order as resln ----
  for (int rr = 0; rr < 16; rr++) {
    const int row = wave * 16 + rr;
    const long m = m0 + row;
    const size_t base = (size_t)m * 256;
    const ushort4 xv = *(const ushort4*)(x + base + lane * 4);
    const ushort4 rv = *(const ushort4*)(smem + row * 264 + lane * 4);
    const float v0 = b2f(xv.x) + b2f(rv.x), v1 = b2f(xv.y) + b2f(rv.y);
    const float v2 = b2f(xv.z) + b2f(rv.z), v3 = b2f(xv.w) + b2f(rv.w);
    float sm = v0 + v1 + v2 + v3;
#pragma unroll
    for (int o = 32; o > 0; o >>= 1) sm += __shfl_xor(sm, o);
    const float mean = sm * (1.f / 256.f);
    const float d0 = v0 - mean, d1 = v1 - mean, d2 = v2 - mean, d3 = v3 - mean;
    float vs = d0 * d0 + d1 * d1 + d2 * d2 + d3 * d3;
#pragma unroll
    for (int o = 32; o > 0; o >>= 1) vs += __shfl_xor(vs, o);
    const float inv = rsqrtf(vs * (1.f / 256.f) + 1e-5f);
    const int c = lane * 4;
    const float o0 = d0 * inv * g[c] + bta[c];
    const float o1 = d1 * inv * g[c + 1] + bta[c + 1];
    const float o2 = d2 * inv * g[c + 2] + bta[c + 2];
    const float o3 = d3 * inv * g[c + 3] + bta[c + 3];
    if (fout) {
      ((float4*)(fout + base))[lane] = make_float4(o0, o1, o2, o3);
    } else {
      ushort4 u;
      u.x = f2b(o0); u.y = f2b(o1); u.z = f2b(o2); u.w = f2b(o3);
      ((ushort4*)(ob + base))[lane] = u;
    }
    if (qb) {
      const ushort4 pv = ((const ushort4*)(pos + base))[lane];
      ushort4 u;
      u.x = f2b(o0 + b2f(pv.x)); u.y = f2b(o1 + b2f(pv.y));
      u.z = f2b(o2 + b2f(pv.z)); u.w = f2b(o3 + b2f(pv.w));
      ((ushort4*)(qb + base))[lane] = u;
    }
  }
}

// ---------------- weight transpose + bf16 convert: [L][K][N] -> [L][N][K] ----------------
__global__ void wtrans_kernel(const float* __restrict__ src, unsigned short* __restrict__ dst,
                              int K, int N, size_t src_lstride, size_t dst_lstride) {
  __shared__ float t[32][33];
  const int tx = threadIdx.x, ty = threadIdx.y;
  const int n0 = blockIdx.x * 32, k0 = blockIdx.y * 32, l = blockIdx.z;
  src += (size_t)l * src_lstride;
  dst += (size_t)l * dst_lstride;
#pragma unroll
  for (int i = 0; i < 4; i++) t[ty * 4 + i][tx] = src[(size_t)(k0 + ty * 4 + i) * N + n0 + tx];
  __syncthreads();
#pragma unroll
  for (int i = 0; i < 4; i++)
    dst[(size_t)(n0 + ty * 4 + i) * K + k0 + tx] = f2b(t[tx][ty * 4 + i]);
}

// ---------------- flatten [B,C,H,W] -> [B,HW,C]; writes residual b16, pos b16, q b16 ----
__global__ void flatten_kernel(const float* __restrict__ src, const float* __restrict__ pos,
                               const float* __restrict__ lemb,
                               unsigned short* __restrict__ outb, unsigned short* __restrict__ posb,
                               unsigned short* __restrict__ qb, int HW, int s0) {
  __shared__ float ts[32][33];
  __shared__ float tp[32][33];
  const int tx = threadIdx.x, ty = threadIdx.y;
  const int hw0 = blockIdx.x * 32, c0 = blockIdx.y * 32, b = blockIdx.z;
  const size_t ibase = ((size_t)b * 256 + c0) * HW + hw0;
#pragma unroll
  for (int i = 0; i < 4; i++) {
    ts[ty * 4 + i][tx] = src[ibase + (size_t)(ty * 4 + i) * HW + tx];
    tp[ty * 4 + i][tx] = pos[ibase + (size_t)(ty * 4 + i) * HW + tx];
  }
  __syncthreads();
#pragma unroll
  for (int i = 0; i < 4; i++) {
    const int sI = s0 + hw0 + ty * 4 + i, c = c0 + tx;
    const size_t o = ((size_t)b * S_TOT + sI) * 256 + c;
    const float sv = ts[tx][ty * 4 + i];
    const unsigned short pb = f2b(tp[tx][ty * 4 + i] + lemb[c]);
    outb[o] = f2b(sv);
    posb[o] = pb;
    qb[o] = f2b(sv + b2f(pb));
  }
}

// ---------------- deformable attention sampling (bf16 value; oa = [offs(192)|aw(96)]) ----
__global__ __launch_bounds__(256) void deform_kernel(const unsigned short* __restrict__ value,
                                                     const unsigned short* __restrict__ oa,
                                                     unsigned short* __restrict__ attn) {
  __shared__ float law[4][96];
  __shared__ uint4 didx[4][96];
  __shared__ float4 dwt[4][96];
  const int tid = threadIdx.x;
  const int wv = tid >> 6, lane = tid & 63;
  const int bs = blockIdx.x * 4 + wv;
  const int b = bs / S_TOT, s = bs - b * S_TOT;

  if (lane < 8) {
    const unsigned short* ap = oa + (size_t)bs * 288 + 192 + lane * 12;
    const uint2 p0 = *(const uint2*)ap;
    const uint2 p1 = *(const uint2*)(ap + 4);
    const uint2 p2 = *(const uint2*)(ap + 8);
    float a[12] = {blo(p0.x), bhi(p0.x), blo(p0.y), bhi(p0.y),
                   blo(p1.x), bhi(p1.x), blo(p1.y), bhi(p1.y),
                   blo(p2.x), bhi(p2.x), blo(p2.y), bhi(p2.y)};
    float mx = a[0];
#pragma unroll
    for (int i = 1; i < 12; i++) mx = fmaxf(mx, a[i]);
    float e[12], sm = 0.f;
#pragma unroll
    for (int i = 0; i < 12; i++) { e[i] = __expf(a[i] - mx); sm += e[i]; }
    const float r = 1.f / sm;
#pragma unroll
    for (int i = 0; i < 12; i++) law[wv][lane * 12 + i] = e[i] * r;
  }
  __syncthreads();

  float rx, ry;
  {
    if (s < 1024) { const int li = s; rx = ((li & 31) + 0.5f) * (1.f / 32); ry = ((li >> 5) + 0.5f) * (1.f / 32); }
    else if (s < 5120) { const int li = s - 1024; rx = ((li & 63) + 0.5f) * (1.f / 64); ry = ((li >> 6) + 0.5f) * (1.f / 64); }
    else { const int li = s - 5120; rx = ((li & 127) + 0.5f) * (1.f / 128); ry = ((li >> 7) + 0.5f) * (1.f / 128); }
  }

  for (int ti = lane; ti < 96; ti += 64) {
    const int h = ti / 12;
    const int rem = ti - h * 12;
    const int lvl = rem >> 2;
    const int wl = 32 << lvl;
    const float fwl = (float)wl;
    const int start = (lvl == 0) ? 0 : ((lvl == 1) ? 1024 : 5120);
    const unsigned op = *(const unsigned*)(oa + (size_t)bs * 288 + 2 * ti);
    const float ox = blo(op), oy = bhi(op);
    const float x = (rx + ox / fwl) * fwl - 0.5f;
    const float y = (ry + oy / fwl) * fwl - 0.5f;
    const float xf = floorf(x), yf = floorf(y);
    const int x0 = (int)xf, y0 = (int)yf;
    const float fx = x - xf, fy = y - yf;
    const bool xv0 = (x0 >= 0) & (x0 < wl), xv1 = (x0 + 1 >= 0) & (x0 + 1 < wl);
    const bool yv0 = (y0 >= 0) & (y0 < wl), yv1 = (y0 + 1 >= 0) & (y0 + 1 < wl);
    const int x0c = min(max(x0, 0), wl - 1), x1c = min(max(x0 + 1, 0), wl - 1);
    const int y0c = min(max(y0, 0), wl - 1), y1c = min(max(y0 + 1, 0), wl - 1);
    const float w = law[wv][ti];
    float4 w4;
    w4.x = (xv0 & yv0) ? w * (1.f - fx) * (1.f - fy) : 0.f;
    w4.y = (xv1 & yv0) ? w * fx * (1.f - fy) : 0.f;
    w4.z = (xv0 & yv1) ? w * (1.f - fx) * fy : 0.f;
    w4.w = (xv1 & yv1) ? w * fx * fy : 0.f;
    const unsigned base = (unsigned)(((b * S_TOT + start) << 8) + h * 32) * 2u;
    uint4 iv;
    iv.x = base + (unsigned)(y0c * wl + x0c) * 512u;
    iv.y = base + (unsigned)(y0c * wl + x1c) * 512u;
    iv.z = base + (unsigned)(y1c * wl + x0c) * 512u;
    iv.w = base + (unsigned)(y1c * wl + x1c) * 512u;
    didx[wv][ti] = iv;
    dwt[wv][ti] = w4;
  }
  __syncthreads();

  const int h = lane >> 3, c = (lane & 7) * 4;
  const char* vb = (const char*)value + c * 2;
  const uint4* ip = &didx[wv][h * 12];
  const float4* wp = &dwt[wv][h * 12];
  f32x2 acc0 = (f32x2){0.f, 0.f}, acc1 = (f32x2){0.f, 0.f};
#pragma unroll
  for (int t = 0; t < 12; t++) {
    const uint4 iv = ip[t];
    const float4 w4 = wp[t];
    const uint2 q00 = *(const uint2*)(vb + iv.x);
    const uint2 q01 = *(const uint2*)(vb + iv.y);
    const uint2 q10 = *(const uint2*)(vb + iv.z);
    const uint2 q11 = *(const uint2*)(vb + iv.w);
    const f32x2 w0 = (f32x2){w4.x, w4.x}, w1 = (f32x2){w4.y, w4.y};
    const f32x2 w2 = (f32x2){w4.z, w4.z}, w3 = (f32x2){w4.w, w4.w};
    acc0 += w0 * unpk(q00.x) + w1 * unpk(q01.x) + w2 * unpk(q10.x) + w3 * unpk(q11.x);
    acc1 += w0 * unpk(q00.y) + w1 * unpk(q01.y) + w2 * unpk(q10.y) + w3 * unpk(q11.y);
  }
  uint2 o;
  o.x = (unsigned)f2b(acc0.x) | ((unsigned)f2b(acc0.y) << 16);
  o.y = (unsigned)f2b(acc1.x) | ((unsigned)f2b(acc1.y) << 16);
  *(uint2*)(attn + (size_t)bs * 256 + h * 32 + c) = o;
}

// ---------------- host ----------------
extern "C" void kernel_launch(void* const* d_in, const int* in_sizes, int n_in,
                              void* d_out, int out_size, void* d_ws, size_t ws_size,
                              hipStream_t stream) {
  (void)in_sizes; (void)n_in; (void)out_size;
  const float* src0 = (const float*)d_in[0];
  const float* pos0 = (const float*)d_in[1];
  const float* src1 = (const float*)d_in[2];
  const float* pos1 = (const float*)d_in[3];
  const float* src2 = (const float*)d_in[4];
  const float* pos2 = (const float*)d_in[5];
  const float* lemb = (const float*)d_in[6];
  const float* Wv = (const float*)d_in[7];   const float* bv = (const float*)d_in[8];
  const float* Wo = (const float*)d_in[9];   const float* bo = (const float*)d_in[10];
  const float* Wa = (const float*)d_in[11];  const float* ba = (const float*)d_in[12];
  const float* Wout = (const float*)d_in[13]; const float* bout = (const float*)d_in[14];
  const float* ln1g = (const float*)d_in[15]; const float* ln1b = (const float*)d_in[16];
  const float* W1 = (const float*)d_in[17];  const float* b1 = (const float*)d_in[18];
  const float* W2 = (const float*)d_in[19];  const float* b2 = (const float*)d_in[20];
  const float* ln2g = (const float*)d_in[21]; const float* ln2b = (const float*)d_in[22];

  const size_t M = M_TOK;
  const size_t SZ16 = 44040192ull;           // M*256*2
  const size_t POOL = 176160768ull;          // M*1024*2
  const size_t NEED = SZ16 + POOL + SZ16 + SZ16 + 8749056ull;   // 316.8 MB
  if (ws_size < NEED) return;

  char* ws = (char*)d_ws;
  unsigned short* valb = (unsigned short*)ws;      // 44 MB (value only; resln fused away)
  char* pool = ws + SZ16;
  unsigned short* q_b16 = (unsigned short*)pool;
  unsigned short* oa_b16 = (unsigned short*)pool + M * 256;   // [M,288]: offs|aw
  unsigned short* attn_b16 = (unsigned short*)pool + M * 544;
  unsigned short* h_b16 = (unsigned short*)pool;  // clobbers q/oa/attn (dead by then)
  unsigned short* out_b16 = (unsigned short*)(pool + POOL);
  unsigned short* pos_b16 = out_b16 + M * 256;
  unsigned short* wt = pos_b16 + M * 256;

  unsigned short* wtv = wt;                 // [6][256][256]
  unsigned short* wtoa = wt + 393216;       // [6][288][256] (Wo rows 0..191, Wa 192..287)
  unsigned short* wtw = wt + 835584;        // [6][256][256]
  unsigned short* wt1 = wt + 1228800;       // [6][1024][256]
  unsigned short* wt2 = wt + 2801664;       // [6][256][1024]

  const dim3 b32(32, 8);
  wtrans_kernel<<<dim3(8, 8, 6), b32, 0, stream>>>(Wv, wtv, 256, 256, 65536, 65536);
  wtrans_kernel<<<dim3(6, 8, 6), b32, 0, stream>>>(Wo, wtoa, 256, 192, 49152, 73728);
  wtrans_kernel<<<dim3(3, 8, 6), b32, 0, stream>>>(Wa, wtoa + 192 * 256, 256, 96, 24576, 73728);
  wtrans_kernel<<<dim3(8, 8, 6), b32, 0, stream>>>(Wout, wtw, 256, 256, 65536, 65536);
  wtrans_kernel<<<dim3(32, 8, 6), b32, 0, stream>>>(W1, wt1, 256, 1024, 262144, 262144);
  wtrans_kernel<<<dim3(8, 32, 6), b32, 0, stream>>>(W2, wt2, 1024, 256, 262144, 262144);

  flatten_kernel<<<dim3(32, 8, 4), b32, 0, stream>>>(src0, pos0, lemb, out_b16, pos_b16, q_b16, 1024, 0);
  flatten_kernel<<<dim3(128, 8, 4), b32, 0, stream>>>(src1, pos1, lemb + 256, out_b16, pos_b16, q_b16, 4096, 1024);
  flatten_kernel<<<dim3(512, 8, 4), b32, 0, stream>>>(src2, pos2, lemb + 512, out_b16, pos_b16, q_b16, 16384, 5120);

  for (int l = 0; l < 6; l++) {
    gemm_kernel<0><<<dim3(2, 672), 256, 0, stream>>>(out_b16, wtv + l * 65536, bv + l * 256, bv + l * 256, 256, valb, 256, 256);
    gemm_kernel<0><<<dim3(3, 672), 256, 0, stream>>>(q_b16, wtoa + l * 73728, bo + l * 192, ba + l * 96, 192, oa_b16, 288, 256);
    deform_kernel<<<21504, 256, 0, stream>>>(valb, oa_b16, attn_b16);
    // fused Wout + residual + LN1 (writes out_b16 in place)
    gemm_ln_kernel<<<1344, 256, 0, stream>>>(attn_b16, wtw + l * 65536, bout + l * 256, out_b16,
                                             ln1g + l * 256, ln1b + l * 256, out_b16,
                                             nullptr, nullptr, nullptr, 256);
    gemm_kernel<1><<<dim3(8, 672), 256, 0, stream>>>(out_b16, wt1 + l * 262144, b1 + l * 1024, b1 + l * 1024, 1024, h_b16, 1024, 256);
    // fused W2 + residual + LN2 (+q for next layer; final layer writes f32 d_out)
    if (l < 5) {
      gemm_ln_kernel<<<1344, 256, 0, stream>>>(h_b16, wt2 + l * 262144, b2 + l * 256, out_b16,
                                               ln2g + l * 256, ln2b + l * 256, out_b16,
                                               pos_b16, q_b16, nullptr, 1024);
    } else {
      gemm_ln_kernel<<<1344, 256, 0, stream>>>(h_b16, wt2 + l * 262144, b2 + l * 256, out_b16,
                                               ln2g + l * 256, ln2b + l * 256, nullptr,
                                               nullptr, nullptr, (float*)d_out, 1024);
    }
  }
}

// Round 16
// 2663.819 us; speedup vs baseline: 1.1047x; 1.1047x over previous
//
#include <hip/hip_runtime.h>
#include <stdint.h>

// ---------------- static problem config ----------------
#define S_TOT 21504
#define M_TOK 86016
// levels: (32,32) start 0, (64,64) start 1024, (128,128) start 5120

typedef __attribute__((ext_vector_type(8))) short bf16x8;
typedef __attribute__((ext_vector_type(4))) float f32x4;
typedef __attribute__((ext_vector_type(2))) float f32x2;

__device__ __forceinline__ unsigned short f2b(float f) {
  union { float f; unsigned u; } v; v.f = f;
  unsigned r = v.u + 0x7FFFu + ((v.u >> 16) & 1u);
  return (unsigned short)(r >> 16);
}
__device__ __forceinline__ float b2f(unsigned short h) {
  union { unsigned u; float f; } v; v.u = ((unsigned)h) << 16;
  return v.f;
}
__device__ __forceinline__ float blo(unsigned u) {
  union { unsigned u; float f; } v; v.u = u << 16; return v.f;
}
__device__ __forceinline__ float bhi(unsigned u) {
  union { unsigned u; float f; } v; v.u = u & 0xffff0000u; return v.f;
}
__device__ __forceinline__ f32x2 unpk(unsigned u) {
  union { unsigned u; float f; } lo, hi;
  lo.u = u << 16; hi.u = u & 0xffff0000u;
  return (f32x2){lo.f, hi.f};
}

// ---------------- bf16 MFMA GEMM (round-14 form + XCD swizzle) ----------------
// C[M,N] = A[M,K] * Bt[N,K]^T + bias. BM=BN=128. 1D grid, XCD-aware bijective
// swizzle (nblk % 8 == 0 for all our launches): each XCD gets a contiguous run
// of col-tiles over the same row-panel -> A panel stays in that XCD's L2.
// Coalesced C-write via LDS bounce (round-14, the measured win).
#define LSTR 40
template <int RELU>
__global__ __launch_bounds__(256) void gemm_kernel(
    const unsigned short* __restrict__ A, const unsigned short* __restrict__ Bt,
    const float* __restrict__ bias, const float* __restrict__ bias2, int nsplit,
    unsigned short* __restrict__ C, int N, int K, int ntx) {
  __shared__ unsigned short Alds[128 * LSTR];
  __shared__ unsigned short Blds[128 * LSTR];
  const int tid = threadIdx.x;
  const int wave = tid >> 6, lane = tid & 63;
  // XCD-aware bijective remap (guide T1; nblk multiple of 8)
  const int nblk = gridDim.x, chunk = nblk >> 3;
  const int bid = blockIdx.x;
  const int swz = (bid & 7) * chunk + (bid >> 3);
  const long m0 = (long)(swz / ntx) * 128;
  const int n0 = (swz % ntx) * 128;
  const int wm = (wave >> 1) * 64, wn = (wave & 1) * 64;

  f32x4 acc[4][4];
#pragma unroll
  for (int i = 0; i < 4; i++)
#pragma unroll
    for (int j = 0; j < 4; j++) acc[i][j] = (f32x4){0.f, 0.f, 0.f, 0.f};

  const int ar = tid >> 2, ak = (tid & 3) * 8;
  int brA = n0 + ar;      if (brA >= N) brA = N - 1;  // clamp OOB weight rows
  int brB = n0 + ar + 64; if (brB >= N) brB = N - 1;
  const unsigned short* a0p = A + (m0 + ar) * (long)K + ak;
  const unsigned short* a1p = A + (m0 + ar + 64) * (long)K + ak;
  const unsigned short* b0p = Bt + (long)brA * K + ak;
  const unsigned short* b1p = Bt + (long)brB * K + ak;
  unsigned short* aw0 = Alds + ar * LSTR + ak;
  unsigned short* aw1 = Alds + (ar + 64) * LSTR + ak;
  unsigned short* bw0 = Blds + ar * LSTR + ak;
  unsigned short* bw1 = Blds + (ar + 64) * LSTR + ak;

  uint4 a0 = *(const uint4*)a0p;
  uint4 a1 = *(const uint4*)a1p;
  uint4 b0 = *(const uint4*)b0p;
  uint4 b1 = *(const uint4*)b1p;

  for (int k0 = 0; k0 < K; k0 += 32) {
    if (k0) __syncthreads();  // previous iteration's frag reads must finish
    *(uint4*)aw0 = a0;
    *(uint4*)aw1 = a1;
    *(uint4*)bw0 = b0;
    *(uint4*)bw1 = b1;
    if (k0 + 32 < K) {  // prefetch next K-tile into regs; hides under MFMA below
      a0 = *(const uint4*)(a0p + k0 + 32);
      a1 = *(const uint4*)(a1p + k0 + 32);
      b0 = *(const uint4*)(b0p + k0 + 32);
      b1 = *(const uint4*)(b1p + k0 + 32);
    }
    __syncthreads();

    const int kk = (lane >> 4) * 8;
    bf16x8 af[4], bq[4];
#pragma unroll
    for (int i = 0; i < 4; i++)
      af[i] = *(const bf16x8*)&Alds[(wm + i * 16 + (lane & 15)) * LSTR + kk];
#pragma unroll
    for (int j = 0; j < 4; j++)
      bq[j] = *(const bf16x8*)&Blds[(wn + j * 16 + (lane & 15)) * LSTR + kk];
#pragma unroll
    for (int i = 0; i < 4; i++)
#pragma unroll
      for (int j = 0; j < 4; j++)
        acc[i][j] = __builtin_amdgcn_mfma_f32_16x16x32_bf16(af[i], bq[j], acc[i][j], 0, 0, 0);
  }

  // coalesced C-write via LDS bounce (64 rows x 136 stride)
  unsigned short* stage = Alds;
  const int colb = lane & 15, rowb = (lane >> 4) * 4;
#pragma unroll
  for (int half = 0; half < 2; half++) {
    __syncthreads();
    if (wm == half * 64) {
#pragma unroll
      for (int j = 0; j < 4; j++) {
        const int n = n0 + wn + j * 16 + colb;
        const float bn = (n < N) ? ((n < nsplit) ? bias[n] : bias2[n - nsplit]) : 0.f;
#pragma unroll
        for (int i = 0; i < 4; i++) {
#pragma unroll
          for (int r = 0; r < 4; r++) {
            float v = acc[i][j][r] + bn;
            if (RELU) v = fmaxf(v, 0.f);
            stage[(i * 16 + rowb + r) * 136 + wn + j * 16 + colb] = f2b(v);
          }
        }
      }
    }
    __syncthreads();
#pragma unroll
    for (int t = 0; t < 4; t++) {
      const int idx = t * 256 + tid;
      const int rr = idx >> 4;
      const int cc = (idx & 15) * 8;
      const int n = n0 + cc;
      if (n < N) {  // N % 8 == 0, so n < N implies whole chunk valid
        const long m = m0 + half * 64 + rr;
        *(uint4*)(C + m * N + n) = *(const uint4*)(stage + rr * 136 + cc);
      }
    }
  }
}

// ---------------- weight transpose + bf16 convert: [L][K][N] -> [L][N][K] ----------------
__global__ void wtrans_kernel(const float* __restrict__ src, unsigned short* __restrict__ dst,
                              int K, int N, size_t src_lstride, size_t dst_lstride) {
  __shared__ float t[32][33];
  const int tx = threadIdx.x, ty = threadIdx.y;
  const int n0 = blockIdx.x * 32, k0 = blockIdx.y * 32, l = blockIdx.z;
  src += (size_t)l * src_lstride;
  dst += (size_t)l * dst_lstride;
#pragma unroll
  for (int i = 0; i < 4; i++) t[ty * 4 + i][tx] = src[(size_t)(k0 + ty * 4 + i) * N + n0 + tx];
  __syncthreads();
#pragma unroll
  for (int i = 0; i < 4; i++)
    dst[(size_t)(n0 + ty * 4 + i) * K + k0 + tx] = f2b(t[tx][ty * 4 + i]);
}

// ---------------- flatten [B,C,H,W] -> [B,HW,C]; writes residual b16, pos b16, q b16 ----
__global__ void flatten_kernel(const float* __restrict__ src, const float* __restrict__ pos,
                               const float* __restrict__ lemb,
                               unsigned short* __restrict__ outb, unsigned short* __restrict__ posb,
                               unsigned short* __restrict__ qb, int HW, int s0) {
  __shared__ float ts[32][33];
  __shared__ float tp[32][33];
  const int tx = threadIdx.x, ty = threadIdx.y;
  const int hw0 = blockIdx.x * 32, c0 = blockIdx.y * 32, b = blockIdx.z;
  const size_t ibase = ((size_t)b * 256 + c0) * HW + hw0;
#pragma unroll
  for (int i = 0; i < 4; i++) {
    ts[ty * 4 + i][tx] = src[ibase + (size_t)(ty * 4 + i) * HW + tx];
    tp[ty * 4 + i][tx] = pos[ibase + (size_t)(ty * 4 + i) * HW + tx];
  }
  __syncthreads();
#pragma unroll
  for (int i = 0; i < 4; i++) {
    const int sI = s0 + hw0 + ty * 4 + i, c = c0 + tx;
    const size_t o = ((size_t)b * S_TOT + sI) * 256 + c;
    const float sv = ts[tx][ty * 4 + i];
    const unsigned short pb = f2b(tp[tx][ty * 4 + i] + lemb[c]);
    outb[o] = f2b(sv);
    posb[o] = pb;
    qb[o] = f2b(sv + b2f(pb));
  }
}

// ---------------- deformable attention sampling (bf16 value; oa = [offs(192)|aw(96)]) ----
__global__ __launch_bounds__(256) void deform_kernel(const unsigned short* __restrict__ value,
                                                     const unsigned short* __restrict__ oa,
                                                     unsigned short* __restrict__ attn) {
  __shared__ float law[4][96];
  __shared__ uint4 didx[4][96];
  __shared__ float4 dwt[4][96];
  const int tid = threadIdx.x;
  const int wv = tid >> 6, lane = tid & 63;
  const int bs = blockIdx.x * 4 + wv;
  const int b = bs / S_TOT, s = bs - b * S_TOT;

  if (lane < 8) {  // per-head softmax over NL*NP=12
    const unsigned short* ap = oa + (size_t)bs * 288 + 192 + lane * 12;
    const uint2 p0 = *(const uint2*)ap;
    const uint2 p1 = *(const uint2*)(ap + 4);
    const uint2 p2 = *(const uint2*)(ap + 8);
    float a[12] = {blo(p0.x), bhi(p0.x), blo(p0.y), bhi(p0.y),
                   blo(p1.x), bhi(p1.x), blo(p1.y), bhi(p1.y),
                   blo(p2.x), bhi(p2.x), blo(p2.y), bhi(p2.y)};
    float mx = a[0];
#pragma unroll
    for (int i = 1; i < 12; i++) mx = fmaxf(mx, a[i]);
    float e[12], sm = 0.f;
#pragma unroll
    for (int i = 0; i < 12; i++) { e[i] = __expf(a[i] - mx); sm += e[i]; }
    const float r = 1.f / sm;
#pragma unroll
    for (int i = 0; i < 12; i++) law[wv][lane * 12 + i] = e[i] * r;
  }
  __syncthreads();

  float rx, ry;
  {
    if (s < 1024) { const int li = s; rx = ((li & 31) + 0.5f) * (1.f / 32); ry = ((li >> 5) + 0.5f) * (1.f / 32); }
    else if (s < 5120) { const int li = s - 1024; rx = ((li & 63) + 0.5f) * (1.f / 64); ry = ((li >> 6) + 0.5f) * (1.f / 64); }
    else { const int li = s - 5120; rx = ((li & 127) + 0.5f) * (1.f / 128); ry = ((li >> 7) + 0.5f) * (1.f / 128); }
  }

  for (int ti = lane; ti < 96; ti += 64) {
    const int h = ti / 12;
    const int rem = ti - h * 12;
    const int lvl = rem >> 2;
    const int wl = 32 << lvl;
    const float fwl = (float)wl;
    const int start = (lvl == 0) ? 0 : ((lvl == 1) ? 1024 : 5120);
    const unsigned op = *(const unsigned*)(oa + (size_t)bs * 288 + 2 * ti);
    const float ox = blo(op), oy = bhi(op);
    const float x = (rx + ox / fwl) * fwl - 0.5f;   // matches ref FP order
    const float y = (ry + oy / fwl) * fwl - 0.5f;
    const float xf = floorf(x), yf = floorf(y);
    const int x0 = (int)xf, y0 = (int)yf;
    const float fx = x - xf, fy = y - yf;
    const bool xv0 = (x0 >= 0) & (x0 < wl), xv1 = (x0 + 1 >= 0) & (x0 + 1 < wl);
    const bool yv0 = (y0 >= 0) & (y0 < wl), yv1 = (y0 + 1 >= 0) & (y0 + 1 < wl);
    const int x0c = min(max(x0, 0), wl - 1), x1c = min(max(x0 + 1, 0), wl - 1);
    const int y0c = min(max(y0, 0), wl - 1), y1c = min(max(y0 + 1, 0), wl - 1);
    const float w = law[wv][ti];
    float4 w4;
    w4.x = (xv0 & yv0) ? w * (1.f - fx) * (1.f - fy) : 0.f;
    w4.y = (xv1 & yv0) ? w * fx * (1.f - fy) : 0.f;
    w4.z = (xv0 & yv1) ? w * (1.f - fx) * fy : 0.f;
    w4.w = (xv1 & yv1) ? w * fx * fy : 0.f;
    // BYTE offsets (x2): gather loop does zero scaling arithmetic.
    const unsigned base = (unsigned)(((b * S_TOT + start) << 8) + h * 32) * 2u;
    uint4 iv;
    iv.x = base + (unsigned)(y0c * wl + x0c) * 512u;
    iv.y = base + (unsigned)(y0c * wl + x1c) * 512u;
    iv.z = base + (unsigned)(y1c * wl + x0c) * 512u;
    iv.w = base + (unsigned)(y1c * wl + x1c) * 512u;
    didx[wv][ti] = iv;
    dwt[wv][ti] = w4;
  }
  __syncthreads();

  const int h = lane >> 3, c = (lane & 7) * 4;
  const char* vb = (const char*)value + c * 2;  // per-lane channel base, hoisted
  const uint4* ip = &didx[wv][h * 12];
  const float4* wp = &dwt[wv][h * 12];
  f32x2 acc0 = (f32x2){0.f, 0.f}, acc1 = (f32x2){0.f, 0.f};
#pragma unroll
  for (int t = 0; t < 12; t++) {
    const uint4 iv = ip[t];
    const float4 w4 = wp[t];
    const uint2 q00 = *(const uint2*)(vb + iv.x);
    const uint2 q01 = *(const uint2*)(vb + iv.y);
    const uint2 q10 = *(const uint2*)(vb + iv.z);
    const uint2 q11 = *(const uint2*)(vb + iv.w);
    const f32x2 w0 = (f32x2){w4.x, w4.x}, w1 = (f32x2){w4.y, w4.y};
    const f32x2 w2 = (f32x2){w4.z, w4.z}, w3 = (f32x2){w4.w, w4.w};
    acc0 += w0 * unpk(q00.x) + w1 * unpk(q01.x) + w2 * unpk(q10.x) + w3 * unpk(q11.x);
    acc1 += w0 * unpk(q00.y) + w1 * unpk(q01.y) + w2 * unpk(q10.y) + w3 * unpk(q11.y);
  }
  uint2 o;
  o.x = (unsigned)f2b(acc0.x) | ((unsigned)f2b(acc0.y) << 16);
  o.y = (unsigned)f2b(acc1.x) | ((unsigned)f2b(acc1.y) << 16);
  *(uint2*)(attn + (size_t)bs * 256 + h * 32 + c) = o;
}

// ---------------- residual + layernorm; bf16 residual stream (in-place) ----------------
__global__ __launch_bounds__(256) void resln_kernel(const unsigned short* __restrict__ x,
                                                    const unsigned short* __restrict__ r,
                                                    const float* __restrict__ g,
                                                    const float* __restrict__ bta,
                                                    unsigned short* __restrict__ ob,
                                                    const unsigned short* __restrict__ pos,
                                                    unsigned short* __restrict__ qb,
                                                    float* __restrict__ fout) {
  const int t = blockIdx.x * 4 + (threadIdx.x >> 6);
  const int lane = threadIdx.x & 63;
  const size_t base = (size_t)t * 256;
  const ushort4 xv = ((const ushort4*)(x + base))[lane];
  const ushort4 rv = ((const ushort4*)(r + base))[lane];
  const float v0 = b2f(xv.x) + b2f(rv.x), v1 = b2f(xv.y) + b2f(rv.y);
  const float v2 = b2f(xv.z) + b2f(rv.z), v3 = b2f(xv.w) + b2f(rv.w);
  float sm = v0 + v1 + v2 + v3;
#pragma unroll
  for (int o = 32; o > 0; o >>= 1) sm += __shfl_xor(sm, o);
  const float mean = sm * (1.f / 256.f);
  const float d0 = v0 - mean, d1 = v1 - mean, d2 = v2 - mean, d3 = v3 - mean;
  float vs = d0 * d0 + d1 * d1 + d2 * d2 + d3 * d3;
#pragma unroll
  for (int o = 32; o > 0; o >>= 1) vs += __shfl_xor(vs, o);
  const float inv = rsqrtf(vs * (1.f / 256.f) + 1e-5f);
  const int c = lane * 4;
  const float o0 = d0 * inv * g[c] + bta[c];
  const float o1 = d1 * inv * g[c + 1] + bta[c + 1];
  const float o2 = d2 * inv * g[c + 2] + bta[c + 2];
  const float o3 = d3 * inv * g[c + 3] + bta[c + 3];
  if (fout) {
    ((float4*)(fout + base))[lane] = make_float4(o0, o1, o2, o3);
  } else {
    ushort4 u;
    u.x = f2b(o0); u.y = f2b(o1); u.z = f2b(o2); u.w = f2b(o3);
    ((ushort4*)(ob + base))[lane] = u;
  }
  if (qb) {
    const ushort4 pv = ((const ushort4*)(pos + base))[lane];
    ushort4 u;
    u.x = f2b(o0 + b2f(pv.x)); u.y = f2b(o1 + b2f(pv.y));
    u.z = f2b(o2 + b2f(pv.z)); u.w = f2b(o3 + b2f(pv.w));
    ((ushort4*)(qb + base))[lane] = u;
  }
}

// ---------------- host ----------------
extern "C" void kernel_launch(void* const* d_in, const int* in_sizes, int n_in,
                              void* d_out, int out_size, void* d_ws, size_t ws_size,
                              hipStream_t stream) {
  (void)in_sizes; (void)n_in; (void)out_size;
  const float* src0 = (const float*)d_in[0];
  const float* pos0 = (const float*)d_in[1];
  const float* src1 = (const float*)d_in[2];
  const float* pos1 = (const float*)d_in[3];
  const float* src2 = (const float*)d_in[4];
  const float* pos2 = (const float*)d_in[5];
  const float* lemb = (const float*)d_in[6];
  const float* Wv = (const float*)d_in[7];   const float* bv = (const float*)d_in[8];
  const float* Wo = (const float*)d_in[9];   const float* bo = (const float*)d_in[10];
  const float* Wa = (const float*)d_in[11];  const float* ba = (const float*)d_in[12];
  const float* Wout = (const float*)d_in[13]; const float* bout = (const float*)d_in[14];
  const float* ln1g = (const float*)d_in[15]; const float* ln1b = (const float*)d_in[16];
  const float* W1 = (const float*)d_in[17];  const float* b1 = (const float*)d_in[18];
  const float* W2 = (const float*)d_in[19];  const float* b2 = (const float*)d_in[20];
  const float* ln2g = (const float*)d_in[21]; const float* ln2b = (const float*)d_in[22];

  const size_t M = M_TOK;
  const size_t SZ16 = 44040192ull;           // M*256*2
  const size_t POOL = 176160768ull;          // M*1024*2
  const size_t NEED = SZ16 + POOL + SZ16 + SZ16 + 8749056ull;   // 316.8 MB
  if (ws_size < NEED) return;

  char* ws = (char*)d_ws;
  unsigned short* slot0b = (unsigned short*)ws;   // 44 MB: value -> wout -> ff (serial reuse)
  unsigned short* valb = slot0b;
  unsigned short* woutb = slot0b;
  unsigned short* ffb = slot0b;
  char* pool = ws + SZ16;
  unsigned short* q_b16 = (unsigned short*)pool;
  unsigned short* oa_b16 = (unsigned short*)pool + M * 256;   // [M,288]: offs|aw
  unsigned short* attn_b16 = (unsigned short*)pool + M * 544;
  unsigned short* h_b16 = (unsigned short*)pool;  // clobbers q/oa/attn (dead by then)
  unsigned short* out_b16 = (unsigned short*)(pool + POOL);
  unsigned short* pos_b16 = out_b16 + M * 256;
  unsigned short* wt = pos_b16 + M * 256;

  unsigned short* wtv = wt;                 // [6][256][256]
  unsigned short* wtoa = wt + 393216;       // [6][288][256] (Wo rows 0..191, Wa 192..287)
  unsigned short* wtw = wt + 835584;        // [6][256][256]
  unsigned short* wt1 = wt + 1228800;       // [6][1024][256]
  unsigned short* wt2 = wt + 2801664;       // [6][256][1024]

  const dim3 b32(32, 8);
  wtrans_kernel<<<dim3(8, 8, 6), b32, 0, stream>>>(Wv, wtv, 256, 256, 65536, 65536);
  wtrans_kernel<<<dim3(6, 8, 6), b32, 0, stream>>>(Wo, wtoa, 256, 192, 49152, 73728);
  wtrans_kernel<<<dim3(3, 8, 6), b32, 0, stream>>>(Wa, wtoa + 192 * 256, 256, 96, 24576, 73728);
  wtrans_kernel<<<dim3(8, 8, 6), b32, 0, stream>>>(Wout, wtw, 256, 256, 65536, 65536);
  wtrans_kernel<<<dim3(32, 8, 6), b32, 0, stream>>>(W1, wt1, 256, 1024, 262144, 262144);
  wtrans_kernel<<<dim3(8, 32, 6), b32, 0, stream>>>(W2, wt2, 1024, 256, 262144, 262144);

  flatten_kernel<<<dim3(32, 8, 4), b32, 0, stream>>>(src0, pos0, lemb, out_b16, pos_b16, q_b16, 1024, 0);
  flatten_kernel<<<dim3(128, 8, 4), b32, 0, stream>>>(src1, pos1, lemb + 256, out_b16, pos_b16, q_b16, 4096, 1024);
  flatten_kernel<<<dim3(512, 8, 4), b32, 0, stream>>>(src2, pos2, lemb + 512, out_b16, pos_b16, q_b16, 16384, 5120);

  for (int l = 0; l < 6; l++) {
    gemm_kernel<0><<<1344, 256, 0, stream>>>(out_b16, wtv + l * 65536, bv + l * 256, bv + l * 256, 256, valb, 256, 256, 2);
    gemm_kernel<0><<<2016, 256, 0, stream>>>(q_b16, wtoa + l * 73728, bo + l * 192, ba + l * 96, 192, oa_b16, 288, 256, 3);
    deform_kernel<<<21504, 256, 0, stream>>>(valb, oa_b16, attn_b16);
    gemm_kernel<0><<<1344, 256, 0, stream>>>(attn_b16, wtw + l * 65536, bout + l * 256, bout + l * 256, 256, woutb, 256, 256, 2);
    resln_kernel<<<21504, 256, 0, stream>>>(out_b16, woutb, ln1g + l * 256, ln1b + l * 256, out_b16, nullptr, nullptr, nullptr);
    gemm_kernel<1><<<5376, 256, 0, stream>>>(out_b16, wt1 + l * 262144, b1 + l * 1024, b1 + l * 1024, 1024, h_b16, 1024, 256, 8);
    gemm_kernel<0><<<1344, 256, 0, stream>>>(h_b16, wt2 + l * 262144, b2 + l * 256, b2 + l * 256, 256, ffb, 256, 1024, 2);
    if (l < 5) {
      resln_kernel<<<21504, 256, 0, stream>>>(out_b16, ffb, ln2g + l * 256, ln2b + l * 256, out_b16, pos_b16, q_b16, nullptr);
    } else {
      resln_kernel<<<21504, 256, 0, stream>>>(out_b16, ffb, ln2g + l * 256, ln2b + l * 256, nullptr, nullptr, nullptr, (float*)d_out);
    }
  }
}

// Round 17
// 2659.706 us; speedup vs baseline: 1.1064x; 1.0015x over previous
//
#include <hip/hip_runtime.h>
#include <stdint.h>

// ---------------- static problem config ----------------
#define S_TOT 21504
#define M_TOK 86016
// levels: (32,32) start 0, (64,64) start 1024, (128,128) start 5120

typedef __attribute__((ext_vector_type(8))) short bf16x8;
typedef __attribute__((ext_vector_type(4))) float f32x4;
typedef __attribute__((ext_vector_type(2))) float f32x2;

__device__ __forceinline__ unsigned short f2b(float f) {
  union { float f; unsigned u; } v; v.f = f;
  unsigned r = v.u + 0x7FFFu + ((v.u >> 16) & 1u);
  return (unsigned short)(r >> 16);
}
__device__ __forceinline__ float b2f(unsigned short h) {
  union { unsigned u; float f; } v; v.u = ((unsigned)h) << 16;
  return v.f;
}
__device__ __forceinline__ float blo(unsigned u) {
  union { unsigned u; float f; } v; v.u = u << 16; return v.f;
}
__device__ __forceinline__ float bhi(unsigned u) {
  union { unsigned u; float f; } v; v.u = u & 0xffff0000u; return v.f;
}
__device__ __forceinline__ f32x2 unpk(unsigned u) {
  union { unsigned u; float f; } lo, hi;
  lo.u = u << 16; hi.u = u & 0xffff0000u;
  return (f32x2){lo.f, hi.f};
}

// ---------------- bf16 MFMA GEMM (round-14 form + XCD swizzle) ----------------
// C[M,N] = A[M,K] * Bt[N,K]^T + bias. BM=BN=128. 1D grid, XCD-aware bijective
// swizzle (nblk % 8 == 0 for all our launches): each XCD gets a contiguous run
// of col-tiles over the same row-panel -> A panel stays in that XCD's L2.
// Coalesced C-write via LDS bounce (round-14, the measured win).
#define LSTR 40
template <int RELU>
__global__ __launch_bounds__(256) void gemm_kernel(
    const unsigned short* __restrict__ A, const unsigned short* __restrict__ Bt,
    const float* __restrict__ bias, const float* __restrict__ bias2, int nsplit,
    unsigned short* __restrict__ C, int N, int K, int ntx) {
  __shared__ unsigned short Alds[128 * LSTR];
  __shared__ unsigned short Blds[128 * LSTR];
  const int tid = threadIdx.x;
  const int wave = tid >> 6, lane = tid & 63;
  // XCD-aware bijective remap (guide T1; nblk multiple of 8)
  const int nblk = gridDim.x, chunk = nblk >> 3;
  const int bid = blockIdx.x;
  const int swz = (bid & 7) * chunk + (bid >> 3);
  const long m0 = (long)(swz / ntx) * 128;
  const int n0 = (swz % ntx) * 128;
  const int wm = (wave >> 1) * 64, wn = (wave & 1) * 64;

  f32x4 acc[4][4];
#pragma unroll
  for (int i = 0; i < 4; i++)
#pragma unroll
    for (int j = 0; j < 4; j++) acc[i][j] = (f32x4){0.f, 0.f, 0.f, 0.f};

  const int ar = tid >> 2, ak = (tid & 3) * 8;
  int brA = n0 + ar;      if (brA >= N) brA = N - 1;  // clamp OOB weight rows
  int brB = n0 + ar + 64; if (brB >= N) brB = N - 1;
  const unsigned short* a0p = A + (m0 + ar) * (long)K + ak;
  const unsigned short* a1p = A + (m0 + ar + 64) * (long)K + ak;
  const unsigned short* b0p = Bt + (long)brA * K + ak;
  const unsigned short* b1p = Bt + (long)brB * K + ak;
  unsigned short* aw0 = Alds + ar * LSTR + ak;
  unsigned short* aw1 = Alds + (ar + 64) * LSTR + ak;
  unsigned short* bw0 = Blds + ar * LSTR + ak;
  unsigned short* bw1 = Blds + (ar + 64) * LSTR + ak;

  uint4 a0 = *(const uint4*)a0p;
  uint4 a1 = *(const uint4*)a1p;
  uint4 b0 = *(const uint4*)b0p;
  uint4 b1 = *(const uint4*)b1p;

  for (int k0 = 0; k0 < K; k0 += 32) {
    if (k0) __syncthreads();  // previous iteration's frag reads must finish
    *(uint4*)aw0 = a0;
    *(uint4*)aw1 = a1;
    *(uint4*)bw0 = b0;
    *(uint4*)bw1 = b1;
    if (k0 + 32 < K) {  // prefetch next K-tile into regs; hides under MFMA below
      a0 = *(const uint4*)(a0p + k0 + 32);
      a1 = *(const uint4*)(a1p + k0 + 32);
      b0 = *(const uint4*)(b0p + k0 + 32);
      b1 = *(const uint4*)(b1p + k0 + 32);
    }
    __syncthreads();

    const int kk = (lane >> 4) * 8;
    bf16x8 af[4], bq[4];
#pragma unroll
    for (int i = 0; i < 4; i++)
      af[i] = *(const bf16x8*)&Alds[(wm + i * 16 + (lane & 15)) * LSTR + kk];
#pragma unroll
    for (int j = 0; j < 4; j++)
      bq[j] = *(const bf16x8*)&Blds[(wn + j * 16 + (lane & 15)) * LSTR + kk];
#pragma unroll
    for (int i = 0; i < 4; i++)
#pragma unroll
      for (int j = 0; j < 4; j++)
        acc[i][j] = __builtin_amdgcn_mfma_f32_16x16x32_bf16(af[i], bq[j], acc[i][j], 0, 0, 0);
  }

  // coalesced C-write via LDS bounce (64 rows x 136 stride)
  unsigned short* stage = Alds;
  const int colb = lane & 15, rowb = (lane >> 4) * 4;
#pragma unroll
  for (int half = 0; half < 2; half++) {
    __syncthreads();
    if (wm == half * 64) {
#pragma unroll
      for (int j = 0; j < 4; j++) {
        const int n = n0 + wn + j * 16 + colb;
        const float bn = (n < N) ? ((n < nsplit) ? bias[n] : bias2[n - nsplit]) : 0.f;
#pragma unroll
        for (int i = 0; i < 4; i++) {
#pragma unroll
          for (int r = 0; r < 4; r++) {
            float v = acc[i][j][r] + bn;
            if (RELU) v = fmaxf(v, 0.f);
            stage[(i * 16 + rowb + r) * 136 + wn + j * 16 + colb] = f2b(v);
          }
        }
      }
    }
    __syncthreads();
#pragma unroll
    for (int t = 0; t < 4; t++) {
      const int idx = t * 256 + tid;
      const int rr = idx >> 4;
      const int cc = (idx & 15) * 8;
      const int n = n0 + cc;
      if (n < N) {  // N % 8 == 0, so n < N implies whole chunk valid
        const long m = m0 + half * 64 + rr;
        *(uint4*)(C + m * N + n) = *(const uint4*)(stage + rr * 136 + cc);
      }
    }
  }
}

// ---------------- weight transpose + bf16 convert: [L][K][N] -> [L][N][K] ----------------
__global__ void wtrans_kernel(const float* __restrict__ src, unsigned short* __restrict__ dst,
                              int K, int N, size_t src_lstride, size_t dst_lstride) {
  __shared__ float t[32][33];
  const int tx = threadIdx.x, ty = threadIdx.y;
  const int n0 = blockIdx.x * 32, k0 = blockIdx.y * 32, l = blockIdx.z;
  src += (size_t)l * src_lstride;
  dst += (size_t)l * dst_lstride;
#pragma unroll
  for (int i = 0; i < 4; i++) t[ty * 4 + i][tx] = src[(size_t)(k0 + ty * 4 + i) * N + n0 + tx];
  __syncthreads();
#pragma unroll
  for (int i = 0; i < 4; i++)
    dst[(size_t)(n0 + ty * 4 + i) * K + k0 + tx] = f2b(t[tx][ty * 4 + i]);
}

// ---------------- flatten [B,C,H,W] -> [B,HW,C]; writes residual b16, pos b16, q b16 ----
__global__ void flatten_kernel(const float* __restrict__ src, const float* __restrict__ pos,
                               const float* __restrict__ lemb,
                               unsigned short* __restrict__ outb, unsigned short* __restrict__ posb,
                               unsigned short* __restrict__ qb, int HW, int s0) {
  __shared__ float ts[32][33];
  __shared__ float tp[32][33];
  const int tx = threadIdx.x, ty = threadIdx.y;
  const int hw0 = blockIdx.x * 32, c0 = blockIdx.y * 32, b = blockIdx.z;
  const size_t ibase = ((size_t)b * 256 + c0) * HW + hw0;
#pragma unroll
  for (int i = 0; i < 4; i++) {
    ts[ty * 4 + i][tx] = src[ibase + (size_t)(ty * 4 + i) * HW + tx];
    tp[ty * 4 + i][tx] = pos[ibase + (size_t)(ty * 4 + i) * HW + tx];
  }
  __syncthreads();
#pragma unroll
  for (int i = 0; i < 4; i++) {
    const int sI = s0 + hw0 + ty * 4 + i, c = c0 + tx;
    const size_t o = ((size_t)b * S_TOT + sI) * 256 + c;
    const float sv = ts[tx][ty * 4 + i];
    const unsigned short pb = f2b(tp[tx][ty * 4 + i] + lemb[c]);
    outb[o] = f2b(sv);
    posb[o] = pb;
    qb[o] = f2b(sv + b2f(pb));
  }
}

// ---------------- deformable attention sampling (bf16 value; oa = [offs(192)|aw(96)]) ----
__global__ __launch_bounds__(256) void deform_kernel(const unsigned short* __restrict__ value,
                                                     const unsigned short* __restrict__ oa,
                                                     unsigned short* __restrict__ attn) {
  __shared__ float law[4][96];
  __shared__ uint4 didx[4][96];
  __shared__ float4 dwt[4][96];
  const int tid = threadIdx.x;
  const int wv = tid >> 6, lane = tid & 63;
  const int bs = blockIdx.x * 4 + wv;
  const int b = bs / S_TOT, s = bs - b * S_TOT;

  if (lane < 8) {  // per-head softmax over NL*NP=12
    const unsigned short* ap = oa + (size_t)bs * 288 + 192 + lane * 12;
    const uint2 p0 = *(const uint2*)ap;
    const uint2 p1 = *(const uint2*)(ap + 4);
    const uint2 p2 = *(const uint2*)(ap + 8);
    float a[12] = {blo(p0.x), bhi(p0.x), blo(p0.y), bhi(p0.y),
                   blo(p1.x), bhi(p1.x), blo(p1.y), bhi(p1.y),
                   blo(p2.x), bhi(p2.x), blo(p2.y), bhi(p2.y)};
    float mx = a[0];
#pragma unroll
    for (int i = 1; i < 12; i++) mx = fmaxf(mx, a[i]);
    float e[12], sm = 0.f;
#pragma unroll
    for (int i = 0; i < 12; i++) { e[i] = __expf(a[i] - mx); sm += e[i]; }
    const float r = 1.f / sm;
#pragma unroll
    for (int i = 0; i < 12; i++) law[wv][lane * 12 + i] = e[i] * r;
  }
  __syncthreads();

  float rx, ry;
  {
    if (s < 1024) { const int li = s; rx = ((li & 31) + 0.5f) * (1.f / 32); ry = ((li >> 5) + 0.5f) * (1.f / 32); }
    else if (s < 5120) { const int li = s - 1024; rx = ((li & 63) + 0.5f) * (1.f / 64); ry = ((li >> 6) + 0.5f) * (1.f / 64); }
    else { const int li = s - 5120; rx = ((li & 127) + 0.5f) * (1.f / 128); ry = ((li >> 7) + 0.5f) * (1.f / 128); }
  }

  for (int ti = lane; ti < 96; ti += 64) {
    const int h = ti / 12;
    const int rem = ti - h * 12;
    const int lvl = rem >> 2;
    const int wl = 32 << lvl;
    const float fwl = (float)wl;
    const int start = (lvl == 0) ? 0 : ((lvl == 1) ? 1024 : 5120);
    const unsigned op = *(const unsigned*)(oa + (size_t)bs * 288 + 2 * ti);
    const float ox = blo(op), oy = bhi(op);
    const float x = (rx + ox / fwl) * fwl - 0.5f;   // matches ref FP order
    const float y = (ry + oy / fwl) * fwl - 0.5f;
    const float xf = floorf(x), yf = floorf(y);
    const int x0 = (int)xf, y0 = (int)yf;
    const float fx = x - xf, fy = y - yf;
    const bool xv0 = (x0 >= 0) & (x0 < wl), xv1 = (x0 + 1 >= 0) & (x0 + 1 < wl);
    const bool yv0 = (y0 >= 0) & (y0 < wl), yv1 = (y0 + 1 >= 0) & (y0 + 1 < wl);
    const int x0c = min(max(x0, 0), wl - 1), x1c = min(max(x0 + 1, 0), wl - 1);
    const int y0c = min(max(y0, 0), wl - 1), y1c = min(max(y0 + 1, 0), wl - 1);
    const float w = law[wv][ti];
    float4 w4;
    w4.x = (xv0 & yv0) ? w * (1.f - fx) * (1.f - fy) : 0.f;
    w4.y = (xv1 & yv0) ? w * fx * (1.f - fy) : 0.f;
    w4.z = (xv0 & yv1) ? w * (1.f - fx) * fy : 0.f;
    w4.w = (xv1 & yv1) ? w * fx * fy : 0.f;
    // BYTE offsets (x2): gather loop does zero scaling arithmetic.
    const unsigned base = (unsigned)(((b * S_TOT + start) << 8) + h * 32) * 2u;
    uint4 iv;
    iv.x = base + (unsigned)(y0c * wl + x0c) * 512u;
    iv.y = base + (unsigned)(y0c * wl + x1c) * 512u;
    iv.z = base + (unsigned)(y1c * wl + x0c) * 512u;
    iv.w = base + (unsigned)(y1c * wl + x1c) * 512u;
    didx[wv][ti] = iv;
    dwt[wv][ti] = w4;
  }
  __syncthreads();

  const int h = lane >> 3, c = (lane & 7) * 4;
  const char* vb = (const char*)value + c * 2;  // per-lane channel base, hoisted
  const uint4* ip = &didx[wv][h * 12];
  const float4* wp = &dwt[wv][h * 12];
  f32x2 acc0 = (f32x2){0.f, 0.f}, acc1 = (f32x2){0.f, 0.f};
#pragma unroll
  for (int t = 0; t < 12; t++) {
    const uint4 iv = ip[t];
    const float4 w4 = wp[t];
    const uint2 q00 = *(const uint2*)(vb + iv.x);
    const uint2 q01 = *(const uint2*)(vb + iv.y);
    const uint2 q10 = *(const uint2*)(vb + iv.z);
    const uint2 q11 = *(const uint2*)(vb + iv.w);
    const f32x2 w0 = (f32x2){w4.x, w4.x}, w1 = (f32x2){w4.y, w4.y};
    const f32x2 w2 = (f32x2){w4.z, w4.z}, w3 = (f32x2){w4.w, w4.w};
    acc0 += w0 * unpk(q00.x) + w1 * unpk(q01.x) + w2 * unpk(q10.x) + w3 * unpk(q11.x);
    acc1 += w0 * unpk(q00.y) + w1 * unpk(q01.y) + w2 * unpk(q10.y) + w3 * unpk(q11.y);
  }
  uint2 o;
  o.x = (unsigned)f2b(acc0.x) | ((unsigned)f2b(acc0.y) << 16);
  o.y = (unsigned)f2b(acc1.x) | ((unsigned)f2b(acc1.y) << 16);
  *(uint2*)(attn + (size_t)bs * 256 + h * 32 + c) = o;
}

// ---------------- residual + layernorm; bf16 residual stream (in-place) ----------------
__global__ __launch_bounds__(256) void resln_kernel(const unsigned short* __restrict__ x,
                                                    const unsigned short* __restrict__ r,
                                                    const float* __restrict__ g,
                                                    const float* __restrict__ bta,
                                                    unsigned short* __restrict__ ob,
                                                    const unsigned short* __restrict__ pos,
                                                    unsigned short* __restrict__ qb,
                                                    float* __restrict__ fout) {
  const int t = blockIdx.x * 4 + (threadIdx.x >> 6);
  const int lane = threadIdx.x & 63;
  const size_t base = (size_t)t * 256;
  const ushort4 xv = ((const ushort4*)(x + base))[lane];
  const ushort4 rv = ((const ushort4*)(r + base))[lane];
  const float v0 = b2f(xv.x) + b2f(rv.x), v1 = b2f(xv.y) + b2f(rv.y);
  const float v2 = b2f(xv.z) + b2f(rv.z), v3 = b2f(xv.w) + b2f(rv.w);
  float sm = v0 + v1 + v2 + v3;
#pragma unroll
  for (int o = 32; o > 0; o >>= 1) sm += __shfl_xor(sm, o);
  const float mean = sm * (1.f / 256.f);
  const float d0 = v0 - mean, d1 = v1 - mean, d2 = v2 - mean, d3 = v3 - mean;
  float vs = d0 * d0 + d1 * d1 + d2 * d2 + d3 * d3;
#pragma unroll
  for (int o = 32; o > 0; o >>= 1) vs += __shfl_xor(vs, o);
  const float inv = rsqrtf(vs * (1.f / 256.f) + 1e-5f);
  const int c = lane * 4;
  const float o0 = d0 * inv * g[c] + bta[c];
  const float o1 = d1 * inv * g[c + 1] + bta[c + 1];
  const float o2 = d2 * inv * g[c + 2] + bta[c + 2];
  const float o3 = d3 * inv * g[c + 3] + bta[c + 3];
  if (fout) {
    ((float4*)(fout + base))[lane] = make_float4(o0, o1, o2, o3);
  } else {
    ushort4 u;
    u.x = f2b(o0); u.y = f2b(o1); u.z = f2b(o2); u.w = f2b(o3);
    ((ushort4*)(ob + base))[lane] = u;
  }
  if (qb) {
    const ushort4 pv = ((const ushort4*)(pos + base))[lane];
    ushort4 u;
    u.x = f2b(o0 + b2f(pv.x)); u.y = f2b(o1 + b2f(pv.y));
    u.z = f2b(o2 + b2f(pv.z)); u.w = f2b(o3 + b2f(pv.w));
    ((ushort4*)(qb + base))[lane] = u;
  }
}

// ---------------- host ----------------
extern "C" void kernel_launch(void* const* d_in, const int* in_sizes, int n_in,
                              void* d_out, int out_size, void* d_ws, size_t ws_size,
                              hipStream_t stream) {
  (void)in_sizes; (void)n_in; (void)out_size;
  const float* src0 = (const float*)d_in[0];
  const float* pos0 = (const float*)d_in[1];
  const float* src1 = (const float*)d_in[2];
  const float* pos1 = (const float*)d_in[3];
  const float* src2 = (const float*)d_in[4];
  const float* pos2 = (const float*)d_in[5];
  const float* lemb = (const float*)d_in[6];
  const float* Wv = (const float*)d_in[7];   const float* bv = (const float*)d_in[8];
  const float* Wo = (const float*)d_in[9];   const float* bo = (const float*)d_in[10];
  const float* Wa = (const float*)d_in[11];  const float* ba = (const float*)d_in[12];
  const float* Wout = (const float*)d_in[13]; const float* bout = (const float*)d_in[14];
  const float* ln1g = (const float*)d_in[15]; const float* ln1b = (const float*)d_in[16];
  const float* W1 = (const float*)d_in[17];  const float* b1 = (const float*)d_in[18];
  const float* W2 = (const float*)d_in[19];  const float* b2 = (const float*)d_in[20];
  const float* ln2g = (const float*)d_in[21]; const float* ln2b = (const float*)d_in[22];

  const size_t M = M_TOK;
  const size_t SZ16 = 44040192ull;           // M*256*2
  const size_t POOL = 176160768ull;          // M*1024*2
  const size_t NEED = SZ16 + POOL + SZ16 + SZ16 + 8749056ull;   // 316.8 MB
  if (ws_size < NEED) return;

  char* ws = (char*)d_ws;
  unsigned short* slot0b = (unsigned short*)ws;   // 44 MB: value -> wout -> ff (serial reuse)
  unsigned short* valb = slot0b;
  unsigned short* woutb = slot0b;
  unsigned short* ffb = slot0b;
  char* pool = ws + SZ16;
  unsigned short* q_b16 = (unsigned short*)pool;
  unsigned short* oa_b16 = (unsigned short*)pool + M * 256;   // [M,288]: offs|aw
  unsigned short* attn_b16 = (unsigned short*)pool + M * 544;
  unsigned short* h_b16 = (unsigned short*)pool;  // clobbers q/oa/attn (dead by then)
  unsigned short* out_b16 = (unsigned short*)(pool + POOL);
  unsigned short* pos_b16 = out_b16 + M * 256;
  unsigned short* wt = pos_b16 + M * 256;

  unsigned short* wtv = wt;                 // [6][256][256]
  unsigned short* wtoa = wt + 393216;       // [6][288][256] (Wo rows 0..191, Wa 192..287)
  unsigned short* wtw = wt + 835584;        // [6][256][256]
  unsigned short* wt1 = wt + 1228800;       // [6][1024][256]
  unsigned short* wt2 = wt + 2801664;       // [6][256][1024]

  const dim3 b32(32, 8);
  wtrans_kernel<<<dim3(8, 8, 6), b32, 0, stream>>>(Wv, wtv, 256, 256, 65536, 65536);
  wtrans_kernel<<<dim3(6, 8, 6), b32, 0, stream>>>(Wo, wtoa, 256, 192, 49152, 73728);
  wtrans_kernel<<<dim3(3, 8, 6), b32, 0, stream>>>(Wa, wtoa + 192 * 256, 256, 96, 24576, 73728);
  wtrans_kernel<<<dim3(8, 8, 6), b32, 0, stream>>>(Wout, wtw, 256, 256, 65536, 65536);
  wtrans_kernel<<<dim3(32, 8, 6), b32, 0, stream>>>(W1, wt1, 256, 1024, 262144, 262144);
  wtrans_kernel<<<dim3(8, 32, 6), b32, 0, stream>>>(W2, wt2, 1024, 256, 262144, 262144);

  flatten_kernel<<<dim3(32, 8, 4), b32, 0, stream>>>(src0, pos0, lemb, out_b16, pos_b16, q_b16, 1024, 0);
  flatten_kernel<<<dim3(128, 8, 4), b32, 0, stream>>>(src1, pos1, lemb + 256, out_b16, pos_b16, q_b16, 4096, 1024);
  flatten_kernel<<<dim3(512, 8, 4), b32, 0, stream>>>(src2, pos2, lemb + 512, out_b16, pos_b16, q_b16, 16384, 5120);

  for (int l = 0; l < 6; l++) {
    gemm_kernel<0><<<1344, 256, 0, stream>>>(out_b16, wtv + l * 65536, bv + l * 256, bv + l * 256, 256, valb, 256, 256, 2);
    gemm_kernel<0><<<2016, 256, 0, stream>>>(q_b16, wtoa + l * 73728, bo + l * 192, ba + l * 96, 192, oa_b16, 288, 256, 3);
    deform_kernel<<<21504, 256, 0, stream>>>(valb, oa_b16, attn_b16);
    gemm_kernel<0><<<1344, 256, 0, stream>>>(attn_b16, wtw + l * 65536, bout + l * 256, bout + l * 256, 256, woutb, 256, 256, 2);
    resln_kernel<<<21504, 256, 0, stream>>>(out_b16, woutb, ln1g + l * 256, ln1b + l * 256, out_b16, nullptr, nullptr, nullptr);
    gemm_kernel<1><<<5376, 256, 0, stream>>>(out_b16, wt1 + l * 262144, b1 + l * 1024, b1 + l * 1024, 1024, h_b16, 1024, 256, 8);
    gemm_kernel<0><<<1344, 256, 0, stream>>>(h_b16, wt2 + l * 262144, b2 + l * 256, b2 + l * 256, 256, ffb, 256, 1024, 2);
    if (l < 5) {
      resln_kernel<<<21504, 256, 0, stream>>>(out_b16, ffb, ln2g + l * 256, ln2b + l * 256, out_b16, pos_b16, q_b16, nullptr);
    } else {
      resln_kernel<<<21504, 256, 0, stream>>>(out_b16, ffb, ln2g + l * 256, ln2b + l * 256, nullptr, nullptr, nullptr, (float*)d_out);
    }
  }
}

// Round 18
// 2657.079 us; speedup vs baseline: 1.1075x; 1.0010x over previous
//
#include <hip/hip_runtime.h>
#include <hip/hip_fp16.h>
#include <stdint.h>

// ---------------- static problem config ----------------
#define S_TOT 21504
#define M_TOK 86016
// levels: (32,32) start 0, (64,64) start 1024, (128,128) start 5120

typedef __attribute__((ext_vector_type(8))) short bf16x8;
typedef __attribute__((ext_vector_type(4))) float f32x4;
typedef __attribute__((ext_vector_type(2))) float f32x2;

__device__ __forceinline__ unsigned short f2b(float f) {
  union { float f; unsigned u; } v; v.f = f;
  unsigned r = v.u + 0x7FFFu + ((v.u >> 16) & 1u);
  return (unsigned short)(r >> 16);
}
__device__ __forceinline__ unsigned short f2h(float f) {
  __half h = __float2half(f);
  return __half_as_ushort(h);
}
__device__ __forceinline__ float b2f(unsigned short h) {
  union { unsigned u; float f; } v; v.u = ((unsigned)h) << 16;
  return v.f;
}
__device__ __forceinline__ float blo(unsigned u) {
  union { unsigned u; float f; } v; v.u = u << 16; return v.f;
}
__device__ __forceinline__ float bhi(unsigned u) {
  union { unsigned u; float f; } v; v.u = u & 0xffff0000u; return v.f;
}
// fp16 pair access; (float)h folds into v_fma_mix_f32 at the consuming fma
__device__ __forceinline__ float h2lo(unsigned u) {
  union { unsigned u; __half2 h; } v; v.u = u; return __half2float(v.h.x);
}
__device__ __forceinline__ float h2hi(unsigned u) {
  union { unsigned u; __half2 h; } v; v.u = u; return __half2float(v.h.y);
}

// ---------------- bf16 MFMA GEMM (round-17 form): C = A * Bt^T + bias ----------------
// BM=BN=128. 1D grid with XCD-aware bijective swizzle; coalesced C via LDS bounce.
// OUTH=1 -> C stored as fp16 (value tensor), else bf16.
#define LSTR 40
template <int RELU, int OUTH>
__global__ __launch_bounds__(256) void gemm_kernel(
    const unsigned short* __restrict__ A, const unsigned short* __restrict__ Bt,
    const float* __restrict__ bias, const float* __restrict__ bias2, int nsplit,
    unsigned short* __restrict__ C, int N, int K, int ntx) {
  __shared__ unsigned short Alds[128 * LSTR];
  __shared__ unsigned short Blds[128 * LSTR];
  const int tid = threadIdx.x;
  const int wave = tid >> 6, lane = tid & 63;
  const int nblk = gridDim.x, chunk = nblk >> 3;
  const int bid = blockIdx.x;
  const int swz = (bid & 7) * chunk + (bid >> 3);
  const long m0 = (long)(swz / ntx) * 128;
  const int n0 = (swz % ntx) * 128;
  const int wm = (wave >> 1) * 64, wn = (wave & 1) * 64;

  f32x4 acc[4][4];
#pragma unroll
  for (int i = 0; i < 4; i++)
#pragma unroll
    for (int j = 0; j < 4; j++) acc[i][j] = (f32x4){0.f, 0.f, 0.f, 0.f};

  const int ar = tid >> 2, ak = (tid & 3) * 8;
  int brA = n0 + ar;      if (brA >= N) brA = N - 1;  // clamp OOB weight rows
  int brB = n0 + ar + 64; if (brB >= N) brB = N - 1;
  const unsigned short* a0p = A + (m0 + ar) * (long)K + ak;
  const unsigned short* a1p = A + (m0 + ar + 64) * (long)K + ak;
  const unsigned short* b0p = Bt + (long)brA * K + ak;
  const unsigned short* b1p = Bt + (long)brB * K + ak;
  unsigned short* aw0 = Alds + ar * LSTR + ak;
  unsigned short* aw1 = Alds + (ar + 64) * LSTR + ak;
  unsigned short* bw0 = Blds + ar * LSTR + ak;
  unsigned short* bw1 = Blds + (ar + 64) * LSTR + ak;

  uint4 a0 = *(const uint4*)a0p;
  uint4 a1 = *(const uint4*)a1p;
  uint4 b0 = *(const uint4*)b0p;
  uint4 b1 = *(const uint4*)b1p;

  for (int k0 = 0; k0 < K; k0 += 32) {
    if (k0) __syncthreads();
    *(uint4*)aw0 = a0;
    *(uint4*)aw1 = a1;
    *(uint4*)bw0 = b0;
    *(uint4*)bw1 = b1;
    if (k0 + 32 < K) {
      a0 = *(const uint4*)(a0p + k0 + 32);
      a1 = *(const uint4*)(a1p + k0 + 32);
      b0 = *(const uint4*)(b0p + k0 + 32);
      b1 = *(const uint4*)(b1p + k0 + 32);
    }
    __syncthreads();

    const int kk = (lane >> 4) * 8;
    bf16x8 af[4], bq[4];
#pragma unroll
    for (int i = 0; i < 4; i++)
      af[i] = *(const bf16x8*)&Alds[(wm + i * 16 + (lane & 15)) * LSTR + kk];
#pragma unroll
    for (int j = 0; j < 4; j++)
      bq[j] = *(const bf16x8*)&Blds[(wn + j * 16 + (lane & 15)) * LSTR + kk];
#pragma unroll
    for (int i = 0; i < 4; i++)
#pragma unroll
      for (int j = 0; j < 4; j++)
        acc[i][j] = __builtin_amdgcn_mfma_f32_16x16x32_bf16(af[i], bq[j], acc[i][j], 0, 0, 0);
  }

  // coalesced C-write via LDS bounce (64 rows x 136 stride)
  unsigned short* stage = Alds;
  const int colb = lane & 15, rowb = (lane >> 4) * 4;
#pragma unroll
  for (int half = 0; half < 2; half++) {
    __syncthreads();
    if (wm == half * 64) {
#pragma unroll
      for (int j = 0; j < 4; j++) {
        const int n = n0 + wn + j * 16 + colb;
        const float bn = (n < N) ? ((n < nsplit) ? bias[n] : bias2[n - nsplit]) : 0.f;
#pragma unroll
        for (int i = 0; i < 4; i++) {
#pragma unroll
          for (int r = 0; r < 4; r++) {
            float v = acc[i][j][r] + bn;
            if (RELU) v = fmaxf(v, 0.f);
            stage[(i * 16 + rowb + r) * 136 + wn + j * 16 + colb] = OUTH ? f2h(v) : f2b(v);
          }
        }
      }
    }
    __syncthreads();
#pragma unroll
    for (int t = 0; t < 4; t++) {
      const int idx = t * 256 + tid;
      const int rr = idx >> 4;
      const int cc = (idx & 15) * 8;
      const int n = n0 + cc;
      if (n < N) {
        const long m = m0 + half * 64 + rr;
        *(uint4*)(C + m * N + n) = *(const uint4*)(stage + rr * 136 + cc);
      }
    }
  }
}

// ---------------- weight transpose + bf16 convert: [L][K][N] -> [L][N][K] ----------------
__global__ void wtrans_kernel(const float* __restrict__ src, unsigned short* __restrict__ dst,
                              int K, int N, size_t src_lstride, size_t dst_lstride) {
  __shared__ float t[32][33];
  const int tx = threadIdx.x, ty = threadIdx.y;
  const int n0 = blockIdx.x * 32, k0 = blockIdx.y * 32, l = blockIdx.z;
  src += (size_t)l * src_lstride;
  dst += (size_t)l * dst_lstride;
#pragma unroll
  for (int i = 0; i < 4; i++) t[ty * 4 + i][tx] = src[(size_t)(k0 + ty * 4 + i) * N + n0 + tx];
  __syncthreads();
#pragma unroll
  for (int i = 0; i < 4; i++)
    dst[(size_t)(n0 + ty * 4 + i) * K + k0 + tx] = f2b(t[tx][ty * 4 + i]);
}

// ---------------- flatten [B,C,H,W] -> [B,HW,C]; writes residual b16, pos b16, q b16 ----
__global__ void flatten_kernel(const float* __restrict__ src, const float* __restrict__ pos,
                               const float* __restrict__ lemb,
                               unsigned short* __restrict__ outb, unsigned short* __restrict__ posb,
                               unsigned short* __restrict__ qb, int HW, int s0) {
  __shared__ float ts[32][33];
  __shared__ float tp[32][33];
  const int tx = threadIdx.x, ty = threadIdx.y;
  const int hw0 = blockIdx.x * 32, c0 = blockIdx.y * 32, b = blockIdx.z;
  const size_t ibase = ((size_t)b * 256 + c0) * HW + hw0;
#pragma unroll
  for (int i = 0; i < 4; i++) {
    ts[ty * 4 + i][tx] = src[ibase + (size_t)(ty * 4 + i) * HW + tx];
    tp[ty * 4 + i][tx] = pos[ibase + (size_t)(ty * 4 + i) * HW + tx];
  }
  __syncthreads();
#pragma unroll
  for (int i = 0; i < 4; i++) {
    const int sI = s0 + hw0 + ty * 4 + i, c = c0 + tx;
    const size_t o = ((size_t)b * S_TOT + sI) * 256 + c;
    const float sv = ts[tx][ty * 4 + i];
    const unsigned short pb = f2b(tp[tx][ty * 4 + i] + lemb[c]);
    outb[o] = f2b(sv);
    posb[o] = pb;
    qb[o] = f2b(sv + b2f(pb));
  }
}

// ---------------- deformable attention sampling (fp16 value; oa = [offs(192)|aw(96)]) ----
// Gather uses fp16 values so each channel fma folds to v_fma_mix_f32 (no unpack VALU).
__global__ __launch_bounds__(256) void deform_kernel(const unsigned short* __restrict__ value,
                                                     const unsigned short* __restrict__ oa,
                                                     unsigned short* __restrict__ attn) {
  __shared__ float law[4][96];
  __shared__ uint4 didx[4][96];
  __shared__ float4 dwt[4][96];
  const int tid = threadIdx.x;
  const int wv = tid >> 6, lane = tid & 63;
  const int bs = blockIdx.x * 4 + wv;
  const int b = bs / S_TOT, s = bs - b * S_TOT;

  if (lane < 8) {  // per-head softmax over NL*NP=12
    const unsigned short* ap = oa + (size_t)bs * 288 + 192 + lane * 12;
    const uint2 p0 = *(const uint2*)ap;
    const uint2 p1 = *(const uint2*)(ap + 4);
    const uint2 p2 = *(const uint2*)(ap + 8);
    float a[12] = {blo(p0.x), bhi(p0.x), blo(p0.y), bhi(p0.y),
                   blo(p1.x), bhi(p1.x), blo(p1.y), bhi(p1.y),
                   blo(p2.x), bhi(p2.x), blo(p2.y), bhi(p2.y)};
    float mx = a[0];
#pragma unroll
    for (int i = 1; i < 12; i++) mx = fmaxf(mx, a[i]);
    float e[12], sm = 0.f;
#pragma unroll
    for (int i = 0; i < 12; i++) { e[i] = __expf(a[i] - mx); sm += e[i]; }
    const float r = 1.f / sm;
#pragma unroll
    for (int i = 0; i < 12; i++) law[wv][lane * 12 + i] = e[i] * r;
  }
  __syncthreads();

  float rx, ry;
  {
    if (s < 1024) { const int li = s; rx = ((li & 31) + 0.5f) * (1.f / 32); ry = ((li >> 5) + 0.5f) * (1.f / 32); }
    else if (s < 5120) { const int li = s - 1024; rx = ((li & 63) + 0.5f) * (1.f / 64); ry = ((li >> 6) + 0.5f) * (1.f / 64); }
    else { const int li = s - 5120; rx = ((li & 127) + 0.5f) * (1.f / 128); ry = ((li >> 7) + 0.5f) * (1.f / 128); }
  }

  for (int ti = lane; ti < 96; ti += 64) {
    const int h = ti / 12;
    const int rem = ti - h * 12;
    const int lvl = rem >> 2;
    const int wl = 32 << lvl;
    const float fwl = (float)wl;
    const int start = (lvl == 0) ? 0 : ((lvl == 1) ? 1024 : 5120);
    const unsigned op = *(const unsigned*)(oa + (size_t)bs * 288 + 2 * ti);
    const float ox = blo(op), oy = bhi(op);
    const float x = (rx + ox / fwl) * fwl - 0.5f;   // matches ref FP order
    const float y = (ry + oy / fwl) * fwl - 0.5f;
    const float xf = floorf(x), yf = floorf(y);
    const int x0 = (int)xf, y0 = (int)yf;
    const float fx = x - xf, fy = y - yf;
    const bool xv0 = (x0 >= 0) & (x0 < wl), xv1 = (x0 + 1 >= 0) & (x0 + 1 < wl);
    const bool yv0 = (y0 >= 0) & (y0 < wl), yv1 = (y0 + 1 >= 0) & (y0 + 1 < wl);
    const int x0c = min(max(x0, 0), wl - 1), x1c = min(max(x0 + 1, 0), wl - 1);
    const int y0c = min(max(y0, 0), wl - 1), y1c = min(max(y0 + 1, 0), wl - 1);
    const float w = law[wv][ti];
    float4 w4;
    w4.x = (xv0 & yv0) ? w * (1.f - fx) * (1.f - fy) : 0.f;
    w4.y = (xv1 & yv0) ? w * fx * (1.f - fy) : 0.f;
    w4.z = (xv0 & yv1) ? w * (1.f - fx) * fy : 0.f;
    w4.w = (xv1 & yv1) ? w * fx * fy : 0.f;
    // BYTE offsets (x2): gather loop does zero scaling arithmetic.
    const unsigned base = (unsigned)(((b * S_TOT + start) << 8) + h * 32) * 2u;
    uint4 iv;
    iv.x = base + (unsigned)(y0c * wl + x0c) * 512u;
    iv.y = base + (unsigned)(y0c * wl + x1c) * 512u;
    iv.z = base + (unsigned)(y1c * wl + x0c) * 512u;
    iv.w = base + (unsigned)(y1c * wl + x1c) * 512u;
    didx[wv][ti] = iv;
    dwt[wv][ti] = w4;
  }
  __syncthreads();

  const int h = lane >> 3, c = (lane & 7) * 4;
  const char* vb = (const char*)value + c * 2;  // per-lane channel base, hoisted
  const uint4* ip = &didx[wv][h * 12];
  const float4* wp = &dwt[wv][h * 12];
  float a0 = 0.f, a1 = 0.f, a2 = 0.f, a3 = 0.f;
#pragma unroll
  for (int t = 0; t < 12; t++) {
    const uint4 iv = ip[t];
    const float4 w4 = wp[t];
    const uint2 q00 = *(const uint2*)(vb + iv.x);
    const uint2 q01 = *(const uint2*)(vb + iv.y);
    const uint2 q10 = *(const uint2*)(vb + iv.z);
    const uint2 q11 = *(const uint2*)(vb + iv.w);
    a0 += w4.x * h2lo(q00.x); a1 += w4.x * h2hi(q00.x);
    a2 += w4.x * h2lo(q00.y); a3 += w4.x * h2hi(q00.y);
    a0 += w4.y * h2lo(q01.x); a1 += w4.y * h2hi(q01.x);
    a2 += w4.y * h2lo(q01.y); a3 += w4.y * h2hi(q01.y);
    a0 += w4.z * h2lo(q10.x); a1 += w4.z * h2hi(q10.x);
    a2 += w4.z * h2lo(q10.y); a3 += w4.z * h2hi(q10.y);
    a0 += w4.w * h2lo(q11.x); a1 += w4.w * h2hi(q11.x);
    a2 += w4.w * h2lo(q11.y); a3 += w4.w * h2hi(q11.y);
  }
  uint2 o;
  o.x = (unsigned)f2b(a0) | ((unsigned)f2b(a1) << 16);
  o.y = (unsigned)f2b(a2) | ((unsigned)f2b(a3) << 16);
  *(uint2*)(attn + (size_t)bs * 256 + h * 32 + c) = o;
}

// ---------------- residual + layernorm; bf16 residual stream (in-place) ----------------
__global__ __launch_bounds__(256) void resln_kernel(const unsigned short* __restrict__ x,
                                                    const unsigned short* __restrict__ r,
                                                    const float* __restrict__ g,
                                                    const float* __restrict__ bta,
                                                    unsigned short* __restrict__ ob,
                                                    const unsigned short* __restrict__ pos,
                                                    unsigned short* __restrict__ qb,
                                                    float* __restrict__ fout) {
  const int t = blockIdx.x * 4 + (threadIdx.x >> 6);
  const int lane = threadIdx.x & 63;
  const size_t base = (size_t)t * 256;
  const ushort4 xv = ((const ushort4*)(x + base))[lane];
  const ushort4 rv = ((const ushort4*)(r + base))[lane];
  const float v0 = b2f(xv.x) + b2f(rv.x), v1 = b2f(xv.y) + b2f(rv.y);
  const float v2 = b2f(xv.z) + b2f(rv.z), v3 = b2f(xv.w) + b2f(rv.w);
  float sm = v0 + v1 + v2 + v3;
#pragma unroll
  for (int o = 32; o > 0; o >>= 1) sm += __shfl_xor(sm, o);
  const float mean = sm * (1.f / 256.f);
  const float d0 = v0 - mean, d1 = v1 - mean, d2 = v2 - mean, d3 = v3 - mean;
  float vs = d0 * d0 + d1 * d1 + d2 * d2 + d3 * d3;
#pragma unroll
  for (int o = 32; o > 0; o >>= 1) vs += __shfl_xor(vs, o);
  const float inv = rsqrtf(vs * (1.f / 256.f) + 1e-5f);
  const int c = lane * 4;
  const float o0 = d0 * inv * g[c] + bta[c];
  const float o1 = d1 * inv * g[c + 1] + bta[c + 1];
  const float o2 = d2 * inv * g[c + 2] + bta[c + 2];
  const float o3 = d3 * inv * g[c + 3] + bta[c + 3];
  if (fout) {
    ((float4*)(fout + base))[lane] = make_float4(o0, o1, o2, o3);
  } else {
    ushort4 u;
    u.x = f2b(o0); u.y = f2b(o1); u.z = f2b(o2); u.w = f2b(o3);
    ((ushort4*)(ob + base))[lane] = u;
  }
  if (qb) {
    const ushort4 pv = ((const ushort4*)(pos + base))[lane];
    ushort4 u;
    u.x = f2b(o0 + b2f(pv.x)); u.y = f2b(o1 + b2f(pv.y));
    u.z = f2b(o2 + b2f(pv.z)); u.w = f2b(o3 + b2f(pv.w));
    ((ushort4*)(qb + base))[lane] = u;
  }
}

// ---------------- host ----------------
extern "C" void kernel_launch(void* const* d_in, const int* in_sizes, int n_in,
                              void* d_out, int out_size, void* d_ws, size_t ws_size,
                              hipStream_t stream) {
  (void)in_sizes; (void)n_in; (void)out_size;
  const float* src0 = (const float*)d_in[0];
  const float* pos0 = (const float*)d_in[1];
  const float* src1 = (const float*)d_in[2];
  const float* pos1 = (const float*)d_in[3];
  const float* src2 = (const float*)d_in[4];
  const float* pos2 = (const float*)d_in[5];
  const float* lemb = (const float*)d_in[6];
  const float* Wv = (const float*)d_in[7];   const float* bv = (const float*)d_in[8];
  const float* Wo = (const float*)d_in[9];   const float* bo = (const float*)d_in[10];
  const float* Wa = (const float*)d_in[11];  const float* ba = (const float*)d_in[12];
  const float* Wout = (const float*)d_in[13]; const float* bout = (const float*)d_in[14];
  const float* ln1g = (const float*)d_in[15]; const float* ln1b = (const float*)d_in[16];
  const float* W1 = (const float*)d_in[17];  const float* b1 = (const float*)d_in[18];
  const float* W2 = (const float*)d_in[19];  const float* b2 = (const float*)d_in[20];
  const float* ln2g = (const float*)d_in[21]; const float* ln2b = (const float*)d_in[22];

  const size_t M = M_TOK;
  const size_t SZ16 = 44040192ull;           // M*256*2
  const size_t POOL = 176160768ull;          // M*1024*2
  const size_t NEED = SZ16 + POOL + SZ16 + SZ16 + 8749056ull;   // 316.8 MB
  if (ws_size < NEED) return;

  char* ws = (char*)d_ws;
  unsigned short* slot0b = (unsigned short*)ws;   // 44 MB: value -> wout -> ff (serial reuse)
  unsigned short* valb = slot0b;
  unsigned short* woutb = slot0b;
  unsigned short* ffb = slot0b;
  char* pool = ws + SZ16;
  unsigned short* q_b16 = (unsigned short*)pool;
  unsigned short* oa_b16 = (unsigned short*)pool + M * 256;   // [M,288]: offs|aw
  unsigned short* attn_b16 = (unsigned short*)pool + M * 544;
  unsigned short* h_b16 = (unsigned short*)pool;  // clobbers q/oa/attn (dead by then)
  unsigned short* out_b16 = (unsigned short*)(pool + POOL);
  unsigned short* pos_b16 = out_b16 + M * 256;
  unsigned short* wt = pos_b16 + M * 256;

  unsigned short* wtv = wt;                 // [6][256][256]
  unsigned short* wtoa = wt + 393216;       // [6][288][256] (Wo rows 0..191, Wa 192..287)
  unsigned short* wtw = wt + 835584;        // [6][256][256]
  unsigned short* wt1 = wt + 1228800;       // [6][1024][256]
  unsigned short* wt2 = wt + 2801664;       // [6][256][1024]

  const dim3 b32(32, 8);
  wtrans_kernel<<<dim3(8, 8, 6), b32, 0, stream>>>(Wv, wtv, 256, 256, 65536, 65536);
  wtrans_kernel<<<dim3(6, 8, 6), b32, 0, stream>>>(Wo, wtoa, 256, 192, 49152, 73728);
  wtrans_kernel<<<dim3(3, 8, 6), b32, 0, stream>>>(Wa, wtoa + 192 * 256, 256, 96, 24576, 73728);
  wtrans_kernel<<<dim3(8, 8, 6), b32, 0, stream>>>(Wout, wtw, 256, 256, 65536, 65536);
  wtrans_kernel<<<dim3(32, 8, 6), b32, 0, stream>>>(W1, wt1, 256, 1024, 262144, 262144);
  wtrans_kernel<<<dim3(8, 32, 6), b32, 0, stream>>>(W2, wt2, 1024, 256, 262144, 262144);

  flatten_kernel<<<dim3(32, 8, 4), b32, 0, stream>>>(src0, pos0, lemb, out_b16, pos_b16, q_b16, 1024, 0);
  flatten_kernel<<<dim3(128, 8, 4), b32, 0, stream>>>(src1, pos1, lemb + 256, out_b16, pos_b16, q_b16, 4096, 1024);
  flatten_kernel<<<dim3(512, 8, 4), b32, 0, stream>>>(src2, pos2, lemb + 512, out_b16, pos_b16, q_b16, 16384, 5120);

  for (int l = 0; l < 6; l++) {
    gemm_kernel<0, 1><<<1344, 256, 0, stream>>>(out_b16, wtv + l * 65536, bv + l * 256, bv + l * 256, 256, valb, 256, 256, 2);
    gemm_kernel<0, 0><<<2016, 256, 0, stream>>>(q_b16, wtoa + l * 73728, bo + l * 192, ba + l * 96, 192, oa_b16, 288, 256, 3);
    deform_kernel<<<21504, 256, 0, stream>>>(valb, oa_b16, attn_b16);
    gemm_kernel<0, 0><<<1344, 256, 0, stream>>>(attn_b16, wtw + l * 65536, bout + l * 256, bout + l * 256, 256, woutb, 256, 256, 2);
    resln_kernel<<<21504, 256, 0, stream>>>(out_b16, woutb, ln1g + l * 256, ln1b + l * 256, out_b16, nullptr, nullptr, nullptr);
    gemm_kernel<1, 0><<<5376, 256, 0, stream>>>(out_b16, wt1 + l * 262144, b1 + l * 1024, b1 + l * 1024, 1024, h_b16, 1024, 256, 8);
    gemm_kernel<0, 0><<<1344, 256, 0, stream>>>(h_b16, wt2 + l * 262144, b2 + l * 256, b2 + l * 256, 256, ffb, 256, 1024, 2);
    if (l < 5) {
      resln_kernel<<<21504, 256, 0, stream>>>(out_b16, ffb, ln2g + l * 256, ln2b + l * 256, out_b16, pos_b16, q_b16, nullptr);
    } else {
      resln_kernel<<<21504, 256, 0, stream>>>(out_b16, ffb, ln2g + l * 256, ln2b + l * 256, nullptr, nullptr, nullptr, (float*)d_out);
    }
  }
}

// Round 19
// 2649.619 us; speedup vs baseline: 1.1106x; 1.0028x over previous
//
#include <hip/hip_runtime.h>
#include <hip/hip_fp16.h>
#include <stdint.h>

// ---------------- static problem config ----------------
#define S_TOT 21504
#define M_TOK 86016
// levels: (32,32) start 0, (64,64) start 1024, (128,128) start 5120

typedef __attribute__((ext_vector_type(8))) short bf16x8;
typedef __attribute__((ext_vector_type(4))) float f32x4;
typedef __attribute__((ext_vector_type(2))) float f32x2;

__device__ __forceinline__ unsigned short f2b(float f) {
  union { float f; unsigned u; } v; v.f = f;
  unsigned r = v.u + 0x7FFFu + ((v.u >> 16) & 1u);
  return (unsigned short)(r >> 16);
}
__device__ __forceinline__ unsigned short f2h(float f) {
  __half h = __float2half(f);
  return __half_as_ushort(h);
}
__device__ __forceinline__ float b2f(unsigned short h) {
  union { unsigned u; float f; } v; v.u = ((unsigned)h) << 16;
  return v.f;
}
__device__ __forceinline__ float blo(unsigned u) {
  union { unsigned u; float f; } v; v.u = u << 16; return v.f;
}
__device__ __forceinline__ float bhi(unsigned u) {
  union { unsigned u; float f; } v; v.u = u & 0xffff0000u; return v.f;
}
// fp16 pair access; (float)h folds into v_fma_mix_f32 at the consuming fma
__device__ __forceinline__ float h2lo(unsigned u) {
  union { unsigned u; __half2 h; } v; v.u = u; return __half2float(v.h.x);
}
__device__ __forceinline__ float h2hi(unsigned u) {
  union { unsigned u; __half2 h; } v; v.u = u; return __half2float(v.h.y);
}

// ---------------- bf16 MFMA GEMM (round-17 form): C = A * Bt^T + bias ----------------
// BM=BN=128. 1D grid with XCD-aware bijective swizzle; coalesced C via LDS bounce.
// OUTH=1 -> C stored as fp16 (value tensor), else bf16.
#define LSTR 40
template <int RELU, int OUTH>
__global__ __launch_bounds__(256) void gemm_kernel(
    const unsigned short* __restrict__ A, const unsigned short* __restrict__ Bt,
    const float* __restrict__ bias, const float* __restrict__ bias2, int nsplit,
    unsigned short* __restrict__ C, int N, int K, int ntx) {
  __shared__ unsigned short Alds[128 * LSTR];
  __shared__ unsigned short Blds[128 * LSTR];
  const int tid = threadIdx.x;
  const int wave = tid >> 6, lane = tid & 63;
  const int nblk = gridDim.x, chunk = nblk >> 3;
  const int bid = blockIdx.x;
  const int swz = (bid & 7) * chunk + (bid >> 3);
  const long m0 = (long)(swz / ntx) * 128;
  const int n0 = (swz % ntx) * 128;
  const int wm = (wave >> 1) * 64, wn = (wave & 1) * 64;

  f32x4 acc[4][4];
#pragma unroll
  for (int i = 0; i < 4; i++)
#pragma unroll
    for (int j = 0; j < 4; j++) acc[i][j] = (f32x4){0.f, 0.f, 0.f, 0.f};

  const int ar = tid >> 2, ak = (tid & 3) * 8;
  int brA = n0 + ar;      if (brA >= N) brA = N - 1;  // clamp OOB weight rows
  int brB = n0 + ar + 64; if (brB >= N) brB = N - 1;
  const unsigned short* a0p = A + (m0 + ar) * (long)K + ak;
  const unsigned short* a1p = A + (m0 + ar + 64) * (long)K + ak;
  const unsigned short* b0p = Bt + (long)brA * K + ak;
  const unsigned short* b1p = Bt + (long)brB * K + ak;
  unsigned short* aw0 = Alds + ar * LSTR + ak;
  unsigned short* aw1 = Alds + (ar + 64) * LSTR + ak;
  unsigned short* bw0 = Blds + ar * LSTR + ak;
  unsigned short* bw1 = Blds + (ar + 64) * LSTR + ak;

  uint4 a0 = *(const uint4*)a0p;
  uint4 a1 = *(const uint4*)a1p;
  uint4 b0 = *(const uint4*)b0p;
  uint4 b1 = *(const uint4*)b1p;

  for (int k0 = 0; k0 < K; k0 += 32) {
    if (k0) __syncthreads();
    *(uint4*)aw0 = a0;
    *(uint4*)aw1 = a1;
    *(uint4*)bw0 = b0;
    *(uint4*)bw1 = b1;
    if (k0 + 32 < K) {
      a0 = *(const uint4*)(a0p + k0 + 32);
      a1 = *(const uint4*)(a1p + k0 + 32);
      b0 = *(const uint4*)(b0p + k0 + 32);
      b1 = *(const uint4*)(b1p + k0 + 32);
    }
    __syncthreads();

    const int kk = (lane >> 4) * 8;
    bf16x8 af[4], bq[4];
#pragma unroll
    for (int i = 0; i < 4; i++)
      af[i] = *(const bf16x8*)&Alds[(wm + i * 16 + (lane & 15)) * LSTR + kk];
#pragma unroll
    for (int j = 0; j < 4; j++)
      bq[j] = *(const bf16x8*)&Blds[(wn + j * 16 + (lane & 15)) * LSTR + kk];
#pragma unroll
    for (int i = 0; i < 4; i++)
#pragma unroll
      for (int j = 0; j < 4; j++)
        acc[i][j] = __builtin_amdgcn_mfma_f32_16x16x32_bf16(af[i], bq[j], acc[i][j], 0, 0, 0);
  }

  // coalesced C-write via LDS bounce (64 rows x 136 stride)
  unsigned short* stage = Alds;
  const int colb = lane & 15, rowb = (lane >> 4) * 4;
#pragma unroll
  for (int half = 0; half < 2; half++) {
    __syncthreads();
    if (wm == half * 64) {
#pragma unroll
      for (int j = 0; j < 4; j++) {
        const int n = n0 + wn + j * 16 + colb;
        const float bn = (n < N) ? ((n < nsplit) ? bias[n] : bias2[n - nsplit]) : 0.f;
#pragma unroll
        for (int i = 0; i < 4; i++) {
#pragma unroll
          for (int r = 0; r < 4; r++) {
            float v = acc[i][j][r] + bn;
            if (RELU) v = fmaxf(v, 0.f);
            stage[(i * 16 + rowb + r) * 136 + wn + j * 16 + colb] = OUTH ? f2h(v) : f2b(v);
          }
        }
      }
    }
    __syncthreads();
#pragma unroll
    for (int t = 0; t < 4; t++) {
      const int idx = t * 256 + tid;
      const int rr = idx >> 4;
      const int cc = (idx & 15) * 8;
      const int n = n0 + cc;
      if (n < N) {
        const long m = m0 + half * 64 + rr;
        *(uint4*)(C + m * N + n) = *(const uint4*)(stage + rr * 136 + cc);
      }
    }
  }
}

// ---------------- weight transpose + bf16 convert: [L][K][N] -> [L][N][K] ----------------
__global__ void wtrans_kernel(const float* __restrict__ src, unsigned short* __restrict__ dst,
                              int K, int N, size_t src_lstride, size_t dst_lstride) {
  __shared__ float t[32][33];
  const int tx = threadIdx.x, ty = threadIdx.y;
  const int n0 = blockIdx.x * 32, k0 = blockIdx.y * 32, l = blockIdx.z;
  src += (size_t)l * src_lstride;
  dst += (size_t)l * dst_lstride;
#pragma unroll
  for (int i = 0; i < 4; i++) t[ty * 4 + i][tx] = src[(size_t)(k0 + ty * 4 + i) * N + n0 + tx];
  __syncthreads();
#pragma unroll
  for (int i = 0; i < 4; i++)
    dst[(size_t)(n0 + ty * 4 + i) * K + k0 + tx] = f2b(t[tx][ty * 4 + i]);
}

// ---------------- flatten [B,C,H,W] -> [B,HW,C]; writes residual b16, pos b16, q b16 ----
__global__ void flatten_kernel(const float* __restrict__ src, const float* __restrict__ pos,
                               const float* __restrict__ lemb,
                               unsigned short* __restrict__ outb, unsigned short* __restrict__ posb,
                               unsigned short* __restrict__ qb, int HW, int s0) {
  __shared__ float ts[32][33];
  __shared__ float tp[32][33];
  const int tx = threadIdx.x, ty = threadIdx.y;
  const int hw0 = blockIdx.x * 32, c0 = blockIdx.y * 32, b = blockIdx.z;
  const size_t ibase = ((size_t)b * 256 + c0) * HW + hw0;
#pragma unroll
  for (int i = 0; i < 4; i++) {
    ts[ty * 4 + i][tx] = src[ibase + (size_t)(ty * 4 + i) * HW + tx];
    tp[ty * 4 + i][tx] = pos[ibase + (size_t)(ty * 4 + i) * HW + tx];
  }
  __syncthreads();
#pragma unroll
  for (int i = 0; i < 4; i++) {
    const int sI = s0 + hw0 + ty * 4 + i, c = c0 + tx;
    const size_t o = ((size_t)b * S_TOT + sI) * 256 + c;
    const float sv = ts[tx][ty * 4 + i];
    const unsigned short pb = f2b(tp[tx][ty * 4 + i] + lemb[c]);
    outb[o] = f2b(sv);
    posb[o] = pb;
    qb[o] = f2b(sv + b2f(pb));
  }
}

// ---------------- deformable attention sampling (fp16 value; oa = [offs(192)|aw(96)]) ----
// NO inter-wave barriers: every LDS slice (law/didx/dwt) is private to its wave (wv),
// producer->consumer is within-wave through LDS (compiler orders via lgkmcnt).
// Waves proceed independently -> scheduler overlaps stages across waves.
__global__ __launch_bounds__(256) void deform_kernel(const unsigned short* __restrict__ value,
                                                     const unsigned short* __restrict__ oa,
                                                     unsigned short* __restrict__ attn) {
  __shared__ float law[4][96];
  __shared__ uint4 didx[4][96];
  __shared__ float4 dwt[4][96];
  const int tid = threadIdx.x;
  const int wv = tid >> 6, lane = tid & 63;
  const int bs = blockIdx.x * 4 + wv;
  const int b = bs / S_TOT, s = bs - b * S_TOT;

  if (lane < 8) {  // per-head softmax over NL*NP=12
    const unsigned short* ap = oa + (size_t)bs * 288 + 192 + lane * 12;
    const uint2 p0 = *(const uint2*)ap;
    const uint2 p1 = *(const uint2*)(ap + 4);
    const uint2 p2 = *(const uint2*)(ap + 8);
    float a[12] = {blo(p0.x), bhi(p0.x), blo(p0.y), bhi(p0.y),
                   blo(p1.x), bhi(p1.x), blo(p1.y), bhi(p1.y),
                   blo(p2.x), bhi(p2.x), blo(p2.y), bhi(p2.y)};
    float mx = a[0];
#pragma unroll
    for (int i = 1; i < 12; i++) mx = fmaxf(mx, a[i]);
    float e[12], sm = 0.f;
#pragma unroll
    for (int i = 0; i < 12; i++) { e[i] = __expf(a[i] - mx); sm += e[i]; }
    const float r = 1.f / sm;
#pragma unroll
    for (int i = 0; i < 12; i++) law[wv][lane * 12 + i] = e[i] * r;
  }
  // no __syncthreads(): law[wv] is wave-private; lockstep lanes + lgkmcnt order it

  float rx, ry;
  {
    if (s < 1024) { const int li = s; rx = ((li & 31) + 0.5f) * (1.f / 32); ry = ((li >> 5) + 0.5f) * (1.f / 32); }
    else if (s < 5120) { const int li = s - 1024; rx = ((li & 63) + 0.5f) * (1.f / 64); ry = ((li >> 6) + 0.5f) * (1.f / 64); }
    else { const int li = s - 5120; rx = ((li & 127) + 0.5f) * (1.f / 128); ry = ((li >> 7) + 0.5f) * (1.f / 128); }
  }

  for (int ti = lane; ti < 96; ti += 64) {
    const int h = ti / 12;
    const int rem = ti - h * 12;
    const int lvl = rem >> 2;
    const int wl = 32 << lvl;
    const float fwl = (float)wl;
    const int start = (lvl == 0) ? 0 : ((lvl == 1) ? 1024 : 5120);
    const unsigned op = *(const unsigned*)(oa + (size_t)bs * 288 + 2 * ti);
    const float ox = blo(op), oy = bhi(op);
    const float x = (rx + ox / fwl) * fwl - 0.5f;   // matches ref FP order
    const float y = (ry + oy / fwl) * fwl - 0.5f;
    const float xf = floorf(x), yf = floorf(y);
    const int x0 = (int)xf, y0 = (int)yf;
    const float fx = x - xf, fy = y - yf;
    const bool xv0 = (x0 >= 0) & (x0 < wl), xv1 = (x0 + 1 >= 0) & (x0 + 1 < wl);
    const bool yv0 = (y0 >= 0) & (y0 < wl), yv1 = (y0 + 1 >= 0) & (y0 + 1 < wl);
    const int x0c = min(max(x0, 0), wl - 1), x1c = min(max(x0 + 1, 0), wl - 1);
    const int y0c = min(max(y0, 0), wl - 1), y1c = min(max(y0 + 1, 0), wl - 1);
    const float w = law[wv][ti];
    float4 w4;
    w4.x = (xv0 & yv0) ? w * (1.f - fx) * (1.f - fy) : 0.f;
    w4.y = (xv1 & yv0) ? w * fx * (1.f - fy) : 0.f;
    w4.z = (xv0 & yv1) ? w * (1.f - fx) * fy : 0.f;
    w4.w = (xv1 & yv1) ? w * fx * fy : 0.f;
    // BYTE offsets (x2): gather loop does zero scaling arithmetic.
    const unsigned base = (unsigned)(((b * S_TOT + start) << 8) + h * 32) * 2u;
    uint4 iv;
    iv.x = base + (unsigned)(y0c * wl + x0c) * 512u;
    iv.y = base + (unsigned)(y0c * wl + x1c) * 512u;
    iv.z = base + (unsigned)(y1c * wl + x0c) * 512u;
    iv.w = base + (unsigned)(y1c * wl + x1c) * 512u;
    didx[wv][ti] = iv;
    dwt[wv][ti] = w4;
  }
  // no __syncthreads(): didx/dwt[wv] are wave-private

  const int h = lane >> 3, c = (lane & 7) * 4;
  const char* vb = (const char*)value + c * 2;  // per-lane channel base, hoisted
  const uint4* ip = &didx[wv][h * 12];
  const float4* wp = &dwt[wv][h * 12];
  float a0 = 0.f, a1 = 0.f, a2 = 0.f, a3 = 0.f;
#pragma unroll
  for (int t = 0; t < 12; t++) {
    const uint4 iv = ip[t];
    const float4 w4 = wp[t];
    const uint2 q00 = *(const uint2*)(vb + iv.x);
    const uint2 q01 = *(const uint2*)(vb + iv.y);
    const uint2 q10 = *(const uint2*)(vb + iv.z);
    const uint2 q11 = *(const uint2*)(vb + iv.w);
    a0 += w4.x * h2lo(q00.x); a1 += w4.x * h2hi(q00.x);
    a2 += w4.x * h2lo(q00.y); a3 += w4.x * h2hi(q00.y);
    a0 += w4.y * h2lo(q01.x); a1 += w4.y * h2hi(q01.x);
    a2 += w4.y * h2lo(q01.y); a3 += w4.y * h2hi(q01.y);
    a0 += w4.z * h2lo(q10.x); a1 += w4.z * h2hi(q10.x);
    a2 += w4.z * h2lo(q10.y); a3 += w4.z * h2hi(q10.y);
    a0 += w4.w * h2lo(q11.x); a1 += w4.w * h2hi(q11.x);
    a2 += w4.w * h2lo(q11.y); a3 += w4.w * h2hi(q11.y);
  }
  uint2 o;
  o.x = (unsigned)f2b(a0) | ((unsigned)f2b(a1) << 16);
  o.y = (unsigned)f2b(a2) | ((unsigned)f2b(a3) << 16);
  *(uint2*)(attn + (size_t)bs * 256 + h * 32 + c) = o;
}

// ---------------- residual + layernorm; bf16 residual stream (in-place) ----------------
__global__ __launch_bounds__(256) void resln_kernel(const unsigned short* __restrict__ x,
                                                    const unsigned short* __restrict__ r,
                                                    const float* __restrict__ g,
                                                    const float* __restrict__ bta,
                                                    unsigned short* __restrict__ ob,
                                                    const unsigned short* __restrict__ pos,
                                                    unsigned short* __restrict__ qb,
                                                    float* __restrict__ fout) {
  const int t = blockIdx.x * 4 + (threadIdx.x >> 6);
  const int lane = threadIdx.x & 63;
  const size_t base = (size_t)t * 256;
  const ushort4 xv = ((const ushort4*)(x + base))[lane];
  const ushort4 rv = ((const ushort4*)(r + base))[lane];
  const float v0 = b2f(xv.x) + b2f(rv.x), v1 = b2f(xv.y) + b2f(rv.y);
  const float v2 = b2f(xv.z) + b2f(rv.z), v3 = b2f(xv.w) + b2f(rv.w);
  float sm = v0 + v1 + v2 + v3;
#pragma unroll
  for (int o = 32; o > 0; o >>= 1) sm += __shfl_xor(sm, o);
  const float mean = sm * (1.f / 256.f);
  const float d0 = v0 - mean, d1 = v1 - mean, d2 = v2 - mean, d3 = v3 - mean;
  float vs = d0 * d0 + d1 * d1 + d2 * d2 + d3 * d3;
#pragma unroll
  for (int o = 32; o > 0; o >>= 1) vs += __shfl_xor(vs, o);
  const float inv = rsqrtf(vs * (1.f / 256.f) + 1e-5f);
  const int c = lane * 4;
  const float o0 = d0 * inv * g[c] + bta[c];
  const float o1 = d1 * inv * g[c + 1] + bta[c + 1];
  const float o2 = d2 * inv * g[c + 2] + bta[c + 2];
  const float o3 = d3 * inv * g[c + 3] + bta[c + 3];
  if (fout) {
    ((float4*)(fout + base))[lane] = make_float4(o0, o1, o2, o3);
  } else {
    ushort4 u;
    u.x = f2b(o0); u.y = f2b(o1); u.z = f2b(o2); u.w = f2b(o3);
    ((ushort4*)(ob + base))[lane] = u;
  }
  if (qb) {
    const ushort4 pv = ((const ushort4*)(pos + base))[lane];
    ushort4 u;
    u.x = f2b(o0 + b2f(pv.x)); u.y = f2b(o1 + b2f(pv.y));
    u.z = f2b(o2 + b2f(pv.z)); u.w = f2b(o3 + b2f(pv.w));
    ((ushort4*)(qb + base))[lane] = u;
  }
}

// ---------------- host ----------------
extern "C" void kernel_launch(void* const* d_in, const int* in_sizes, int n_in,
                              void* d_out, int out_size, void* d_ws, size_t ws_size,
                              hipStream_t stream) {
  (void)in_sizes; (void)n_in; (void)out_size;
  const float* src0 = (const float*)d_in[0];
  const float* pos0 = (const float*)d_in[1];
  const float* src1 = (const float*)d_in[2];
  const float* pos1 = (const float*)d_in[3];
  const float* src2 = (const float*)d_in[4];
  const float* pos2 = (const float*)d_in[5];
  const float* lemb = (const float*)d_in[6];
  const float* Wv = (const float*)d_in[7];   const float* bv = (const float*)d_in[8];
  const float* Wo = (const float*)d_in[9];   const float* bo = (const float*)d_in[10];
  const float* Wa = (const float*)d_in[11];  const float* ba = (const float*)d_in[12];
  const float* Wout = (const float*)d_in[13]; const float* bout = (const float*)d_in[14];
  const float* ln1g = (const float*)d_in[15]; const float* ln1b = (const float*)d_in[16];
  const float* W1 = (const float*)d_in[17];  const float* b1 = (const float*)d_in[18];
  const float* W2 = (const float*)d_in[19];  const float* b2 = (const float*)d_in[20];
  const float* ln2g = (const float*)d_in[21]; const float* ln2b = (const float*)d_in[22];

  const size_t M = M_TOK;
  const size_t SZ16 = 44040192ull;           // M*256*2
  const size_t POOL = 176160768ull;          // M*1024*2
  const size_t NEED = SZ16 + POOL + SZ16 + SZ16 + 8749056ull;   // 316.8 MB
  if (ws_size < NEED) return;

  char* ws = (char*)d_ws;
  unsigned short* slot0b = (unsigned short*)ws;   // 44 MB: value -> wout -> ff (serial reuse)
  unsigned short* valb = slot0b;
  unsigned short* woutb = slot0b;
  unsigned short* ffb = slot0b;
  char* pool = ws + SZ16;
  unsigned short* q_b16 = (unsigned short*)pool;
  unsigned short* oa_b16 = (unsigned short*)pool + M * 256;   // [M,288]: offs|aw
  unsigned short* attn_b16 = (unsigned short*)pool + M * 544;
  unsigned short* h_b16 = (unsigned short*)pool;  // clobbers q/oa/attn (dead by then)
  unsigned short* out_b16 = (unsigned short*)(pool + POOL);
  unsigned short* pos_b16 = out_b16 + M * 256;
  unsigned short* wt = pos_b16 + M * 256;

  unsigned short* wtv = wt;                 // [6][256][256]
  unsigned short* wtoa = wt + 393216;       // [6][288][256] (Wo rows 0..191, Wa 192..287)
  unsigned short* wtw = wt + 835584;        // [6][256][256]
  unsigned short* wt1 = wt + 1228800;       // [6][1024][256]
  unsigned short* wt2 = wt + 2801664;       // [6][256][1024]

  const dim3 b32(32, 8);
  wtrans_kernel<<<dim3(8, 8, 6), b32, 0, stream>>>(Wv, wtv, 256, 256, 65536, 65536);
  wtrans_kernel<<<dim3(6, 8, 6), b32, 0, stream>>>(Wo, wtoa, 256, 192, 49152, 73728);
  wtrans_kernel<<<dim3(3, 8, 6), b32, 0, stream>>>(Wa, wtoa + 192 * 256, 256, 96, 24576, 73728);
  wtrans_kernel<<<dim3(8, 8, 6), b32, 0, stream>>>(Wout, wtw, 256, 256, 65536, 65536);
  wtrans_kernel<<<dim3(32, 8, 6), b32, 0, stream>>>(W1, wt1, 256, 1024, 262144, 262144);
  wtrans_kernel<<<dim3(8, 32, 6), b32, 0, stream>>>(W2, wt2, 1024, 256, 262144, 262144);

  flatten_kernel<<<dim3(32, 8, 4), b32, 0, stream>>>(src0, pos0, lemb, out_b16, pos_b16, q_b16, 1024, 0);
  flatten_kernel<<<dim3(128, 8, 4), b32, 0, stream>>>(src1, pos1, lemb + 256, out_b16, pos_b16, q_b16, 4096, 1024);
  flatten_kernel<<<dim3(512, 8, 4), b32, 0, stream>>>(src2, pos2, lemb + 512, out_b16, pos_b16, q_b16, 16384, 5120);

  for (int l = 0; l < 6; l++) {
    gemm_kernel<0, 1><<<1344, 256, 0, stream>>>(out_b16, wtv + l * 65536, bv + l * 256, bv + l * 256, 256, valb, 256, 256, 2);
    gemm_kernel<0, 0><<<2016, 256, 0, stream>>>(q_b16, wtoa + l * 73728, bo + l * 192, ba + l * 96, 192, oa_b16, 288, 256, 3);
    deform_kernel<<<21504, 256, 0, stream>>>(valb, oa_b16, attn_b16);
    gemm_kernel<0, 0><<<1344, 256, 0, stream>>>(attn_b16, wtw + l * 65536, bout + l * 256, bout + l * 256, 256, woutb, 256, 256, 2);
    resln_kernel<<<21504, 256, 0, stream>>>(out_b16, woutb, ln1g + l * 256, ln1b + l * 256, out_b16, nullptr, nullptr, nullptr);
    gemm_kernel<1, 0><<<5376, 256, 0, stream>>>(out_b16, wt1 + l * 262144, b1 + l * 1024, b1 + l * 1024, 1024, h_b16, 1024, 256, 8);
    gemm_kernel<0, 0><<<1344, 256, 0, stream>>>(h_b16, wt2 + l * 262144, b2 + l * 256, b2 + l * 256, 256, ffb, 256, 1024, 2);
    if (l < 5) {
      resln_kernel<<<21504, 256, 0, stream>>>(out_b16, ffb, ln2g + l * 256, ln2b + l * 256, out_b16, pos_b16, q_b16, nullptr);
    } else {
      resln_kernel<<<21504, 256, 0, stream>>>(out_b16, ffb, ln2g + l * 256, ln2b + l * 256, nullptr, nullptr, nullptr, (float*)d_out);
    }
  }
}

// Round 20
// 2639.599 us; speedup vs baseline: 1.1148x; 1.0038x over previous
//
#include <hip/hip_runtime.h>
#include <hip/hip_fp16.h>
#include <stdint.h>

// ---------------- static problem config ----------------
#define S_TOT 21504
#define M_TOK 86016
// levels: (32,32) start 0, (64,64) start 1024, (128,128) start 5120

typedef __attribute__((ext_vector_type(8))) short bf16x8;
typedef __attribute__((ext_vector_type(4))) float f32x4;
typedef __attribute__((ext_vector_type(2))) float f32x2;

__device__ __forceinline__ unsigned short f2b(float f) {
  union { float f; unsigned u; } v; v.f = f;
  unsigned r = v.u + 0x7FFFu + ((v.u >> 16) & 1u);
  return (unsigned short)(r >> 16);
}
__device__ __forceinline__ unsigned short f2h(float f) {
  __half h = __float2half(f);
  return __half_as_ushort(h);
}
__device__ __forceinline__ float b2f(unsigned short h) {
  union { unsigned u; float f; } v; v.u = ((unsigned)h) << 16;
  return v.f;
}
__device__ __forceinline__ float blo(unsigned u) {
  union { unsigned u; float f; } v; v.u = u << 16; return v.f;
}
__device__ __forceinline__ float bhi(unsigned u) {
  union { unsigned u; float f; } v; v.u = u & 0xffff0000u; return v.f;
}
// fp16 pair access; (float)h folds into v_fma_mix_f32 at the consuming fma
__device__ __forceinline__ float h2lo(unsigned u) {
  union { unsigned u; __half2 h; } v; v.u = u; return __half2float(v.h.x);
}
__device__ __forceinline__ float h2hi(unsigned u) {
  union { unsigned u; __half2 h; } v; v.u = u; return __half2float(v.h.y);
}

// ---------------- bf16 MFMA GEMM: C = A * Bt^T + bias ----------------
// BM=BN=128, XCD-swizzled 1D grid, coalesced C via LDS bounce (round-17 wins kept).
// NEW: true double-buffered LDS -> ONE barrier per 32-K step (was two). Tile t lives
// in buffer t&1; iteration writes tile t+1 into buf[(t+1)&1] before computing tile t,
// so reads/writes touch different buffers and a single barrier both publishes writes
// and retires reads. K-loop unrolled x2 for compile-time buffer indices.
#define LSTR 40
#define TSZ (128 * LSTR)
template <int RELU, int OUTH>
__global__ __launch_bounds__(256) void gemm_kernel(
    const unsigned short* __restrict__ A, const unsigned short* __restrict__ Bt,
    const float* __restrict__ bias, const float* __restrict__ bias2, int nsplit,
    unsigned short* __restrict__ C, int N, int K, int ntx) {
  __shared__ unsigned short smem[4 * TSZ];  // [A0 | A1 | B0 | B1], 40 KB
  const int tid = threadIdx.x;
  const int wave = tid >> 6, lane = tid & 63;
  const int nblk = gridDim.x, chunk = nblk >> 3;
  const int bid = blockIdx.x;
  const int swz = (bid & 7) * chunk + (bid >> 3);
  const long m0 = (long)(swz / ntx) * 128;
  const int n0 = (swz % ntx) * 128;
  const int wm = (wave >> 1) * 64, wn = (wave & 1) * 64;

  f32x4 acc[4][4];
#pragma unroll
  for (int i = 0; i < 4; i++)
#pragma unroll
    for (int j = 0; j < 4; j++) acc[i][j] = (f32x4){0.f, 0.f, 0.f, 0.f};

  const int ar = tid >> 2, ak = (tid & 3) * 8;
  int brA = n0 + ar;      if (brA >= N) brA = N - 1;  // clamp OOB weight rows
  int brB = n0 + ar + 64; if (brB >= N) brB = N - 1;
  const unsigned short* a0p = A + (m0 + ar) * (long)K + ak;
  const unsigned short* a1p = A + (m0 + ar + 64) * (long)K + ak;
  const unsigned short* b0p = Bt + (long)brA * K + ak;
  const unsigned short* b1p = Bt + (long)brB * K + ak;
  const int wo0 = ar * LSTR + ak, wo1 = (ar + 64) * LSTR + ak;

  uint4 ra0 = *(const uint4*)a0p;
  uint4 ra1 = *(const uint4*)a1p;
  uint4 rb0 = *(const uint4*)b0p;
  uint4 rb1 = *(const uint4*)b1p;
  // tile 0 -> buffers 0
  *(uint4*)(smem + wo0) = ra0;
  *(uint4*)(smem + wo1) = ra1;
  *(uint4*)(smem + 2 * TSZ + wo0) = rb0;
  *(uint4*)(smem + 2 * TSZ + wo1) = rb1;
  if (32 < K) {  // preload tile 1 into regs
    ra0 = *(const uint4*)(a0p + 32);
    ra1 = *(const uint4*)(a1p + 32);
    rb0 = *(const uint4*)(b0p + 32);
    rb1 = *(const uint4*)(b1p + 32);
  }
  __syncthreads();

#define GEMM_COMPUTE(P)                                                               \
  {                                                                                   \
    const int kk = (lane >> 4) * 8;                                                   \
    const unsigned short* Ab = smem + (P)*TSZ;                                        \
    const unsigned short* Bb = smem + (2 + (P)) * TSZ;                                \
    bf16x8 af[4], bq[4];                                                              \
    _Pragma("unroll") for (int i = 0; i < 4; i++)                                     \
        af[i] = *(const bf16x8*)&Ab[(wm + i * 16 + (lane & 15)) * LSTR + kk];         \
    _Pragma("unroll") for (int j = 0; j < 4; j++)                                     \
        bq[j] = *(const bf16x8*)&Bb[(wn + j * 16 + (lane & 15)) * LSTR + kk];         \
    _Pragma("unroll") for (int i = 0; i < 4; i++)                                     \
        _Pragma("unroll") for (int j = 0; j < 4; j++)                                 \
            acc[i][j] = __builtin_amdgcn_mfma_f32_16x16x32_bf16(af[i], bq[j],         \
                                                                acc[i][j], 0, 0, 0); \
  }

  for (int k0 = 0; k0 < K; k0 += 64) {
    // phase 0: tile k0/32 (even) in buf0; stage tile+1 into buf1 first
    if (k0 + 32 < K) {
      *(uint4*)(smem + TSZ + wo0) = ra0;
      *(uint4*)(smem + TSZ + wo1) = ra1;
      *(uint4*)(smem + 3 * TSZ + wo0) = rb0;
      *(uint4*)(smem + 3 * TSZ + wo1) = rb1;
      if (k0 + 64 < K) {
        ra0 = *(const uint4*)(a0p + k0 + 64);
        ra1 = *(const uint4*)(a1p + k0 + 64);
        rb0 = *(const uint4*)(b0p + k0 + 64);
        rb1 = *(const uint4*)(b1p + k0 + 64);
      }
    }
    GEMM_COMPUTE(0);
    __syncthreads();
    // phase 1: tile k0/32+1 (odd) in buf1; stage tile+2 into buf0 first
    if (k0 + 64 < K) {
      *(uint4*)(smem + wo0) = ra0;
      *(uint4*)(smem + wo1) = ra1;
      *(uint4*)(smem + 2 * TSZ + wo0) = rb0;
      *(uint4*)(smem + 2 * TSZ + wo1) = rb1;
      if (k0 + 96 < K) {
        ra0 = *(const uint4*)(a0p + k0 + 96);
        ra1 = *(const uint4*)(a1p + k0 + 96);
        rb0 = *(const uint4*)(b0p + k0 + 96);
        rb1 = *(const uint4*)(b1p + k0 + 96);
      }
    }
    GEMM_COMPUTE(1);
    __syncthreads();
  }
#undef GEMM_COMPUTE

  // coalesced C-write via LDS bounce (64 rows x 136 stride; smem has 20480 ushorts)
  unsigned short* stage = smem;
  const int colb = lane & 15, rowb = (lane >> 4) * 4;
#pragma unroll
  for (int half = 0; half < 2; half++) {
    __syncthreads();
    if (wm == half * 64) {
#pragma unroll
      for (int j = 0; j < 4; j++) {
        const int n = n0 + wn + j * 16 + colb;
        const float bn = (n < N) ? ((n < nsplit) ? bias[n] : bias2[n - nsplit]) : 0.f;
#pragma unroll
        for (int i = 0; i < 4; i++) {
#pragma unroll
          for (int r = 0; r < 4; r++) {
            float v = acc[i][j][r] + bn;
            if (RELU) v = fmaxf(v, 0.f);
            stage[(i * 16 + rowb + r) * 136 + wn + j * 16 + colb] = OUTH ? f2h(v) : f2b(v);
          }
        }
      }
    }
    __syncthreads();
#pragma unroll
    for (int t = 0; t < 4; t++) {
      const int idx = t * 256 + tid;
      const int rr = idx >> 4;
      const int cc = (idx & 15) * 8;
      const int n = n0 + cc;
      if (n < N) {
        const long m = m0 + half * 64 + rr;
        *(uint4*)(C + m * N + n) = *(const uint4*)(stage + rr * 136 + cc);
      }
    }
  }
}

// ---------------- weight transpose + bf16 convert: [L][K][N] -> [L][N][K] ----------------
__global__ void wtrans_kernel(const float* __restrict__ src, unsigned short* __restrict__ dst,
                              int K, int N, size_t src_lstride, size_t dst_lstride) {
  __shared__ float t[32][33];
  const int tx = threadIdx.x, ty = threadIdx.y;
  const int n0 = blockIdx.x * 32, k0 = blockIdx.y * 32, l = blockIdx.z;
  src += (size_t)l * src_lstride;
  dst += (size_t)l * dst_lstride;
#pragma unroll
  for (int i = 0; i < 4; i++) t[ty * 4 + i][tx] = src[(size_t)(k0 + ty * 4 + i) * N + n0 + tx];
  __syncthreads();
#pragma unroll
  for (int i = 0; i < 4; i++)
    dst[(size_t)(n0 + ty * 4 + i) * K + k0 + tx] = f2b(t[tx][ty * 4 + i]);
}

// ---------------- flatten [B,C,H,W] -> [B,HW,C]; writes residual b16, pos b16, q b16 ----
__global__ void flatten_kernel(const float* __restrict__ src, const float* __restrict__ pos,
                               const float* __restrict__ lemb,
                               unsigned short* __restrict__ outb, unsigned short* __restrict__ posb,
                               unsigned short* __restrict__ qb, int HW, int s0) {
  __shared__ float ts[32][33];
  __shared__ float tp[32][33];
  const int tx = threadIdx.x, ty = threadIdx.y;
  const int hw0 = blockIdx.x * 32, c0 = blockIdx.y * 32, b = blockIdx.z;
  const size_t ibase = ((size_t)b * 256 + c0) * HW + hw0;
#pragma unroll
  for (int i = 0; i < 4; i++) {
    ts[ty * 4 + i][tx] = src[ibase + (size_t)(ty * 4 + i) * HW + tx];
    tp[ty * 4 + i][tx] = pos[ibase + (size_t)(ty * 4 + i) * HW + tx];
  }
  __syncthreads();
#pragma unroll
  for (int i = 0; i < 4; i++) {
    const int sI = s0 + hw0 + ty * 4 + i, c = c0 + tx;
    const size_t o = ((size_t)b * S_TOT + sI) * 256 + c;
    const float sv = ts[tx][ty * 4 + i];
    const unsigned short pb = f2b(tp[tx][ty * 4 + i] + lemb[c]);
    outb[o] = f2b(sv);
    posb[o] = pb;
    qb[o] = f2b(sv + b2f(pb));
  }
}

// ---------------- deformable attention sampling (fp16 value; oa = [offs(192)|aw(96)]) ----
// No inter-wave barriers: law/didx/dwt slices are wave-private.
__global__ __launch_bounds__(256) void deform_kernel(const unsigned short* __restrict__ value,
                                                     const unsigned short* __restrict__ oa,
                                                     unsigned short* __restrict__ attn) {
  __shared__ float law[4][96];
  __shared__ uint4 didx[4][96];
  __shared__ float4 dwt[4][96];
  const int tid = threadIdx.x;
  const int wv = tid >> 6, lane = tid & 63;
  const int bs = blockIdx.x * 4 + wv;
  const int b = bs / S_TOT, s = bs - b * S_TOT;

  if (lane < 8) {  // per-head softmax over NL*NP=12
    const unsigned short* ap = oa + (size_t)bs * 288 + 192 + lane * 12;
    const uint2 p0 = *(const uint2*)ap;
    const uint2 p1 = *(const uint2*)(ap + 4);
    const uint2 p2 = *(const uint2*)(ap + 8);
    float a[12] = {blo(p0.x), bhi(p0.x), blo(p0.y), bhi(p0.y),
                   blo(p1.x), bhi(p1.x), blo(p1.y), bhi(p1.y),
                   blo(p2.x), bhi(p2.x), blo(p2.y), bhi(p2.y)};
    float mx = a[0];
#pragma unroll
    for (int i = 1; i < 12; i++) mx = fmaxf(mx, a[i]);
    float e[12], sm = 0.f;
#pragma unroll
    for (int i = 0; i < 12; i++) { e[i] = __expf(a[i] - mx); sm += e[i]; }
    const float r = 1.f / sm;
#pragma unroll
    for (int i = 0; i < 12; i++) law[wv][lane * 12 + i] = e[i] * r;
  }

  float rx, ry;
  {
    if (s < 1024) { const int li = s; rx = ((li & 31) + 0.5f) * (1.f / 32); ry = ((li >> 5) + 0.5f) * (1.f / 32); }
    else if (s < 5120) { const int li = s - 1024; rx = ((li & 63) + 0.5f) * (1.f / 64); ry = ((li >> 6) + 0.5f) * (1.f / 64); }
    else { const int li = s - 5120; rx = ((li & 127) + 0.5f) * (1.f / 128); ry = ((li >> 7) + 0.5f) * (1.f / 128); }
  }

  for (int ti = lane; ti < 96; ti += 64) {
    const int h = ti / 12;
    const int rem = ti - h * 12;
    const int lvl = rem >> 2;
    const int wl = 32 << lvl;
    const float fwl = (float)wl;
    const int start = (lvl == 0) ? 0 : ((lvl == 1) ? 1024 : 5120);
    const unsigned op = *(const unsigned*)(oa + (size_t)bs * 288 + 2 * ti);
    const float ox = blo(op), oy = bhi(op);
    const float x = (rx + ox / fwl) * fwl - 0.5f;   // matches ref FP order
    const float y = (ry + oy / fwl) * fwl - 0.5f;
    const float xf = floorf(x), yf = floorf(y);
    const int x0 = (int)xf, y0 = (int)yf;
    const float fx = x - xf, fy = y - yf;
    const bool xv0 = (x0 >= 0) & (x0 < wl), xv1 = (x0 + 1 >= 0) & (x0 + 1 < wl);
    const bool yv0 = (y0 >= 0) & (y0 < wl), yv1 = (y0 + 1 >= 0) & (y0 + 1 < wl);
    const int x0c = min(max(x0, 0), wl - 1), x1c = min(max(x0 + 1, 0), wl - 1);
    const int y0c = min(max(y0, 0), wl - 1), y1c = min(max(y0 + 1, 0), wl - 1);
    const float w = law[wv][ti];
    float4 w4;
    w4.x = (xv0 & yv0) ? w * (1.f - fx) * (1.f - fy) : 0.f;
    w4.y = (xv1 & yv0) ? w * fx * (1.f - fy) : 0.f;
    w4.z = (xv0 & yv1) ? w * (1.f - fx) * fy : 0.f;
    w4.w = (xv1 & yv1) ? w * fx * fy : 0.f;
    const unsigned base = (unsigned)(((b * S_TOT + start) << 8) + h * 32) * 2u;
    uint4 iv;
    iv.x = base + (unsigned)(y0c * wl + x0c) * 512u;
    iv.y = base + (unsigned)(y0c * wl + x1c) * 512u;
    iv.z = base + (unsigned)(y1c * wl + x0c) * 512u;
    iv.w = base + (unsigned)(y1c * wl + x1c) * 512u;
    didx[wv][ti] = iv;
    dwt[wv][ti] = w4;
  }

  const int h = lane >> 3, c = (lane & 7) * 4;
  const char* vb = (const char*)value + c * 2;
  const uint4* ip = &didx[wv][h * 12];
  const float4* wp = &dwt[wv][h * 12];
  float a0 = 0.f, a1 = 0.f, a2 = 0.f, a3 = 0.f;
#pragma unroll
  for (int t = 0; t < 12; t++) {
    const uint4 iv = ip[t];
    const float4 w4 = wp[t];
    const uint2 q00 = *(const uint2*)(vb + iv.x);
    const uint2 q01 = *(const uint2*)(vb + iv.y);
    const uint2 q10 = *(const uint2*)(vb + iv.z);
    const uint2 q11 = *(const uint2*)(vb + iv.w);
    a0 += w4.x * h2lo(q00.x); a1 += w4.x * h2hi(q00.x);
    a2 += w4.x * h2lo(q00.y); a3 += w4.x * h2hi(q00.y);
    a0 += w4.y * h2lo(q01.x); a1 += w4.y * h2hi(q01.x);
    a2 += w4.y * h2lo(q01.y); a3 += w4.y * h2hi(q01.y);
    a0 += w4.z * h2lo(q10.x); a1 += w4.z * h2hi(q10.x);
    a2 += w4.z * h2lo(q10.y); a3 += w4.z * h2hi(q10.y);
    a0 += w4.w * h2lo(q11.x); a1 += w4.w * h2hi(q11.x);
    a2 += w4.w * h2lo(q11.y); a3 += w4.w * h2hi(q11.y);
  }
  uint2 o;
  o.x = (unsigned)f2b(a0) | ((unsigned)f2b(a1) << 16);
  o.y = (unsigned)f2b(a2) | ((unsigned)f2b(a3) << 16);
  *(uint2*)(attn + (size_t)bs * 256 + h * 32 + c) = o;
}

// ---------------- residual + layernorm; bf16 residual stream (in-place) ----------------
__global__ __launch_bounds__(256) void resln_kernel(const unsigned short* __restrict__ x,
                                                    const unsigned short* __restrict__ r,
                                                    const float* __restrict__ g,
                                                    const float* __restrict__ bta,
                                                    unsigned short* __restrict__ ob,
                                                    const unsigned short* __restrict__ pos,
                                                    unsigned short* __restrict__ qb,
                                                    float* __restrict__ fout) {
  const int t = blockIdx.x * 4 + (threadIdx.x >> 6);
  const int lane = threadIdx.x & 63;
  const size_t base = (size_t)t * 256;
  const ushort4 xv = ((const ushort4*)(x + base))[lane];
  const ushort4 rv = ((const ushort4*)(r + base))[lane];
  const float v0 = b2f(xv.x) + b2f(rv.x), v1 = b2f(xv.y) + b2f(rv.y);
  const float v2 = b2f(xv.z) + b2f(rv.z), v3 = b2f(xv.w) + b2f(rv.w);
  float sm = v0 + v1 + v2 + v3;
#pragma unroll
  for (int o = 32; o > 0; o >>= 1) sm += __shfl_xor(sm, o);
  const float mean = sm * (1.f / 256.f);
  const float d0 = v0 - mean, d1 = v1 - mean, d2 = v2 - mean, d3 = v3 - mean;
  float vs = d0 * d0 + d1 * d1 + d2 * d2 + d3 * d3;
#pragma unroll
  for (int o = 32; o > 0; o >>= 1) vs += __shfl_xor(vs, o);
  const float inv = rsqrtf(vs * (1.f / 256.f) + 1e-5f);
  const int c = lane * 4;
  const float o0 = d0 * inv * g[c] + bta[c];
  const float o1 = d1 * inv * g[c + 1] + bta[c + 1];
  const float o2 = d2 * inv * g[c + 2] + bta[c + 2];
  const float o3 = d3 * inv * g[c + 3] + bta[c + 3];
  if (fout) {
    ((float4*)(fout + base))[lane] = make_float4(o0, o1, o2, o3);
  } else {
    ushort4 u;
    u.x = f2b(o0); u.y = f2b(o1); u.z = f2b(o2); u.w = f2b(o3);
    ((ushort4*)(ob + base))[lane] = u;
  }
  if (qb) {
    const ushort4 pv = ((const ushort4*)(pos + base))[lane];
    ushort4 u;
    u.x = f2b(o0 + b2f(pv.x)); u.y = f2b(o1 + b2f(pv.y));
    u.z = f2b(o2 + b2f(pv.z)); u.w = f2b(o3 + b2f(pv.w));
    ((ushort4*)(qb + base))[lane] = u;
  }
}

// ---------------- host ----------------
extern "C" void kernel_launch(void* const* d_in, const int* in_sizes, int n_in,
                              void* d_out, int out_size, void* d_ws, size_t ws_size,
                              hipStream_t stream) {
  (void)in_sizes; (void)n_in; (void)out_size;
  const float* src0 = (const float*)d_in[0];
  const float* pos0 = (const float*)d_in[1];
  const float* src1 = (const float*)d_in[2];
  const float* pos1 = (const float*)d_in[3];
  const float* src2 = (const float*)d_in[4];
  const float* pos2 = (const float*)d_in[5];
  const float* lemb = (const float*)d_in[6];
  const float* Wv = (const float*)d_in[7];   const float* bv = (const float*)d_in[8];
  const float* Wo = (const float*)d_in[9];   const float* bo = (const float*)d_in[10];
  const float* Wa = (const float*)d_in[11];  const float* ba = (const float*)d_in[12];
  const float* Wout = (const float*)d_in[13]; const float* bout = (const float*)d_in[14];
  const float* ln1g = (const float*)d_in[15]; const float* ln1b = (const float*)d_in[16];
  const float* W1 = (const float*)d_in[17];  const float* b1 = (const float*)d_in[18];
  const float* W2 = (const float*)d_in[19];  const float* b2 = (const float*)d_in[20];
  const float* ln2g = (const float*)d_in[21]; const float* ln2b = (const float*)d_in[22];

  const size_t M = M_TOK;
  const size_t SZ16 = 44040192ull;           // M*256*2
  const size_t POOL = 176160768ull;          // M*1024*2
  const size_t NEED = SZ16 + POOL + SZ16 + SZ16 + 8749056ull;   // 316.8 MB
  if (ws_size < NEED) return;

  char* ws = (char*)d_ws;
  unsigned short* slot0b = (unsigned short*)ws;   // 44 MB: value -> wout -> ff (serial reuse)
  unsigned short* valb = slot0b;
  unsigned short* woutb = slot0b;
  unsigned short* ffb = slot0b;
  char* pool = ws + SZ16;
  unsigned short* q_b16 = (unsigned short*)pool;
  unsigned short* oa_b16 = (unsigned short*)pool + M * 256;   // [M,288]: offs|aw
  unsigned short* attn_b16 = (unsigned short*)pool + M * 544;
  unsigned short* h_b16 = (unsigned short*)pool;  // clobbers q/oa/attn (dead by then)
  unsigned short* out_b16 = (unsigned short*)(pool + POOL);
  unsigned short* pos_b16 = out_b16 + M * 256;
  unsigned short* wt = pos_b16 + M * 256;

  unsigned short* wtv = wt;                 // [6][256][256]
  unsigned short* wtoa = wt + 393216;       // [6][288][256] (Wo rows 0..191, Wa 192..287)
  unsigned short* wtw = wt + 835584;        // [6][256][256]
  unsigned short* wt1 = wt + 1228800;       // [6][1024][256]
  unsigned short* wt2 = wt + 2801664;       // [6][256][1024]

  const dim3 b32(32, 8);
  wtrans_kernel<<<dim3(8, 8, 6), b32, 0, stream>>>(Wv, wtv, 256, 256, 65536, 65536);
  wtrans_kernel<<<dim3(6, 8, 6), b32, 0, stream>>>(Wo, wtoa, 256, 192, 49152, 73728);
  wtrans_kernel<<<dim3(3, 8, 6), b32, 0, stream>>>(Wa, wtoa + 192 * 256, 256, 96, 24576, 73728);
  wtrans_kernel<<<dim3(8, 8, 6), b32, 0, stream>>>(Wout, wtw, 256, 256, 65536, 65536);
  wtrans_kernel<<<dim3(32, 8, 6), b32, 0, stream>>>(W1, wt1, 256, 1024, 262144, 262144);
  wtrans_kernel<<<dim3(8, 32, 6), b32, 0, stream>>>(W2, wt2, 1024, 256, 262144, 262144);

  flatten_kernel<<<dim3(32, 8, 4), b32, 0, stream>>>(src0, pos0, lemb, out_b16, pos_b16, q_b16, 1024, 0);
  flatten_kernel<<<dim3(128, 8, 4), b32, 0, stream>>>(src1, pos1, lemb + 256, out_b16, pos_b16, q_b16, 4096, 1024);
  flatten_kernel<<<dim3(512, 8, 4), b32, 0, stream>>>(src2, pos2, lemb + 512, out_b16, pos_b16, q_b16, 16384, 5120);

  for (int l = 0; l < 6; l++) {
    gemm_kernel<0, 1><<<1344, 256, 0, stream>>>(out_b16, wtv + l * 65536, bv + l * 256, bv + l * 256, 256, valb, 256, 256, 2);
    gemm_kernel<0, 0><<<2016, 256, 0, stream>>>(q_b16, wtoa + l * 73728, bo + l * 192, ba + l * 96, 192, oa_b16, 288, 256, 3);
    deform_kernel<<<21504, 256, 0, stream>>>(valb, oa_b16, attn_b16);
    gemm_kernel<0, 0><<<1344, 256, 0, stream>>>(attn_b16, wtw + l * 65536, bout + l * 256, bout + l * 256, 256, woutb, 256, 256, 2);
    resln_kernel<<<21504, 256, 0, stream>>>(out_b16, woutb, ln1g + l * 256, ln1b + l * 256, out_b16, nullptr, nullptr, nullptr);
    gemm_kernel<1, 0><<<5376, 256, 0, stream>>>(out_b16, wt1 + l * 262144, b1 + l * 1024, b1 + l * 1024, 1024, h_b16, 1024, 256, 8);
    gemm_kernel<0, 0><<<1344, 256, 0, stream>>>(h_b16, wt2 + l * 262144, b2 + l * 256, b2 + l * 256, 256, ffb, 256, 1024, 2);
    if (l < 5) {
      resln_kernel<<<21504, 256, 0, stream>>>(out_b16, ffb, ln2g + l * 256, ln2b + l * 256, out_b16, pos_b16, q_b16, nullptr);
    } else {
      resln_kernel<<<21504, 256, 0, stream>>>(out_b16, ffb, ln2g + l * 256, ln2b + l * 256, nullptr, nullptr, nullptr, (float*)d_out);
    }
  }
}